// Round 1
// baseline (4066.862 us; speedup 1.0000x reference)
//
#include <hip/hip_runtime.h>
#include <hip/hip_bf16.h>

#define B_ 2
#define N_ 4096
#define D_ 512
#define H_ 8
#define M_ (B_*N_)      // 8192 rows
#define SCALE_ 0.125f   // 64^-0.5

// ---------------------------------------------------------------------------
// GEMM: Y = A @ W^T (+bias). A[M_,512] row-major, W[512,512] row-major.
// MODE 0: out[i*512 + j] + bias[j]                (plain, final projection)
// MODE 1: out[((b*H+h)*N + n)*64 + d]             (scatter to [b,h,n,d] for q/k/v)
// Tile: 128(M) x 64(N), BK=16, 256 threads, 8x4 micro-tile per thread.
// ---------------------------------------------------------------------------
template<int MODE>
__global__ __launch_bounds__(256) void gemm_bt(const float* __restrict__ A,
                                               const float* __restrict__ W,
                                               const float* __restrict__ bias,
                                               float* __restrict__ out)
{
    __shared__ float As[16][132];   // [k][m], pad 128+4 keeps float4 alignment (528B rows)
    __shared__ float Bs[16][68];    // [k][n], pad 64+4 (272B rows)

    const int t  = threadIdx.x;
    const int tx = t & 15;          // N direction: 4 cols each
    const int ty = t >> 4;          // M direction: 8 rows each
    const int rowBase = blockIdx.x * 128;
    const int colBase = blockIdx.y * 64;

    float acc[8][4];
#pragma unroll
    for (int i = 0; i < 8; ++i)
#pragma unroll
        for (int j = 0; j < 4; ++j) acc[i][j] = 0.f;

    const int ar = t >> 2;          // 0..63
    const int ac = (t & 3) * 4;     // 0,4,8,12

    for (int k0 = 0; k0 < 512; k0 += 16) {
        // A tile 128x16 (two float4 per thread), B tile 64x16 (one float4)
        float4 a0 = *(const float4*)&A[(size_t)(rowBase + ar) * 512 + k0 + ac];
        float4 a1 = *(const float4*)&A[(size_t)(rowBase + ar + 64) * 512 + k0 + ac];
        float4 b0 = *(const float4*)&W[(size_t)(colBase + ar) * 512 + k0 + ac];
        As[ac + 0][ar] = a0.x; As[ac + 1][ar] = a0.y; As[ac + 2][ar] = a0.z; As[ac + 3][ar] = a0.w;
        As[ac + 0][ar + 64] = a1.x; As[ac + 1][ar + 64] = a1.y; As[ac + 2][ar + 64] = a1.z; As[ac + 3][ar + 64] = a1.w;
        Bs[ac + 0][ar] = b0.x; Bs[ac + 1][ar] = b0.y; Bs[ac + 2][ar] = b0.z; Bs[ac + 3][ar] = b0.w;
        __syncthreads();

#pragma unroll
        for (int kk = 0; kk < 16; ++kk) {
            float4 av0 = *(const float4*)&As[kk][ty * 8];
            float4 av1 = *(const float4*)&As[kk][ty * 8 + 4];
            float4 bv  = *(const float4*)&Bs[kk][tx * 4];
            float aa[8] = {av0.x, av0.y, av0.z, av0.w, av1.x, av1.y, av1.z, av1.w};
            float bb[4] = {bv.x, bv.y, bv.z, bv.w};
#pragma unroll
            for (int i = 0; i < 8; ++i)
#pragma unroll
                for (int j = 0; j < 4; ++j)
                    acc[i][j] = fmaf(aa[i], bb[j], acc[i][j]);
        }
        __syncthreads();
    }

    const int j0 = colBase + tx * 4;
#pragma unroll
    for (int i = 0; i < 8; ++i) {
        const int gi = rowBase + ty * 8 + i;
        float4 r = make_float4(acc[i][0], acc[i][1], acc[i][2], acc[i][3]);
        if (MODE == 0) {
            float4 bv = *(const float4*)&bias[j0];
            r.x += bv.x; r.y += bv.y; r.z += bv.z; r.w += bv.w;
            *(float4*)&out[(size_t)gi * 512 + j0] = r;
        } else {
            const int b = gi >> 12, n = gi & (N_ - 1);
            const int h = j0 >> 6, d = j0 & 63;
            *(float4*)&out[(((size_t)(b * H_ + h) * N_) + n) * 64 + d] = r;
        }
    }
}

// ---------------------------------------------------------------------------
// Flash-style fp32 attention. One block = one (b*h) x 64-row Q tile.
// 256 threads: 64 rows x 4 lane-groups (16 K-columns each). Q row lives in
// registers (pre-scaled); K/V tiles staged in LDS; online softmax per row
// with cross-lane max/sum via shfl_xor(1,2); final 4-lane accumulator reduce.
// Writes output already in [b, n, h*64+d] layout for the final projection.
// ---------------------------------------------------------------------------
__global__ __launch_bounds__(256) void attn_fwd(const float* __restrict__ q,
                                                const float* __restrict__ k,
                                                const float* __restrict__ v,
                                                float* __restrict__ o)
{
    __shared__ float Ks[64][68];
    __shared__ float Vs[64][68];

    const int t  = threadIdx.x;
    const int bh = blockIdx.y;          // 0..15
    const int b  = bh >> 3, h = bh & 7;
    const int r  = t >> 2;              // row within Q tile
    const int cg = t & 3;               // column group (16 cols each)
    const int qrow = blockIdx.x * 64 + r;

    const float* Q = q + (size_t)bh * N_ * 64;
    const float* K = k + (size_t)bh * N_ * 64;
    const float* V = v + (size_t)bh * N_ * 64;

    float qreg[64];
#pragma unroll
    for (int d4 = 0; d4 < 16; ++d4) {
        float4 tq = *(const float4*)&Q[(size_t)qrow * 64 + d4 * 4];
        qreg[d4 * 4 + 0] = tq.x * SCALE_;
        qreg[d4 * 4 + 1] = tq.y * SCALE_;
        qreg[d4 * 4 + 2] = tq.z * SCALE_;
        qreg[d4 * 4 + 3] = tq.w * SCALE_;
    }

    float acc[64];
#pragma unroll
    for (int i = 0; i < 64; ++i) acc[i] = 0.f;
    float m = -3.0e38f, l = 0.f;

    for (int kt = 0; kt < N_ / 64; ++kt) {
#pragma unroll
        for (int i = 0; i < 4; ++i) {
            const int f = t + i * 256;
            const int rr = f >> 4, cc = (f & 15) * 4;
            *(float4*)&Ks[rr][cc] = *(const float4*)&K[(size_t)(kt * 64 + rr) * 64 + cc];
            *(float4*)&Vs[rr][cc] = *(const float4*)&V[(size_t)(kt * 64 + rr) * 64 + cc];
        }
        __syncthreads();

        float p[16];
        float tmax = -3.0e38f;
#pragma unroll
        for (int ci = 0; ci < 16; ++ci) {
            const int c = cg * 16 + ci;
            float s = 0.f;
#pragma unroll
            for (int d4 = 0; d4 < 16; ++d4) {
                float4 kk4 = *(const float4*)&Ks[c][d4 * 4];
                s = fmaf(qreg[d4 * 4 + 0], kk4.x, s);
                s = fmaf(qreg[d4 * 4 + 1], kk4.y, s);
                s = fmaf(qreg[d4 * 4 + 2], kk4.z, s);
                s = fmaf(qreg[d4 * 4 + 3], kk4.w, s);
            }
            p[ci] = s;
            tmax = fmaxf(tmax, s);
        }
        // row max across the 4 lane-groups
        tmax = fmaxf(tmax, __shfl_xor(tmax, 1));
        tmax = fmaxf(tmax, __shfl_xor(tmax, 2));
        const float mnew  = fmaxf(m, tmax);
        const float alpha = __expf(m - mnew);   // m=-big first iter -> 0

        float lsum = 0.f;
#pragma unroll
        for (int ci = 0; ci < 16; ++ci) {
            p[ci] = __expf(p[ci] - mnew);
            lsum += p[ci];
        }
        l = l * alpha + lsum;   // per-lane partial sum (consistent: reduced at end)
        m = mnew;

#pragma unroll
        for (int i = 0; i < 64; ++i) acc[i] *= alpha;

#pragma unroll
        for (int ci = 0; ci < 16; ++ci) {
            const int c = cg * 16 + ci;
            const float pp = p[ci];
#pragma unroll
            for (int d4 = 0; d4 < 16; ++d4) {
                float4 vv = *(const float4*)&Vs[c][d4 * 4];
                acc[d4 * 4 + 0] = fmaf(pp, vv.x, acc[d4 * 4 + 0]);
                acc[d4 * 4 + 1] = fmaf(pp, vv.y, acc[d4 * 4 + 1]);
                acc[d4 * 4 + 2] = fmaf(pp, vv.z, acc[d4 * 4 + 2]);
                acc[d4 * 4 + 3] = fmaf(pp, vv.w, acc[d4 * 4 + 3]);
            }
        }
        __syncthreads();
    }

    // reduce l and acc across the 4 lane-groups of each row
    l += __shfl_xor(l, 1);
    l += __shfl_xor(l, 2);
    const float inv = 1.0f / l;

    float* orow = o + ((size_t)(b * N_ + qrow)) * 512 + h * 64;
#pragma unroll
    for (int i = 0; i < 64; ++i) {
        float s = acc[i];
        s += __shfl_xor(s, 1);
        s += __shfl_xor(s, 2);
        s *= inv;
        if ((i >> 4) == cg) orow[i] = s;   // static index, exec-masked store
    }
}

// ---------------------------------------------------------------------------
extern "C" void kernel_launch(void* const* d_in, const int* in_sizes, int n_in,
                              void* d_out, int out_size, void* d_ws, size_t ws_size,
                              hipStream_t stream)
{
    const float* x  = (const float*)d_in[0];
    const float* Wq = (const float*)d_in[1];
    const float* Wk = (const float*)d_in[2];
    const float* Wv = (const float*)d_in[3];
    const float* Wo = (const float*)d_in[4];
    const float* bo = (const float*)d_in[5];

    float* ws = (float*)d_ws;
    const size_t SZ = (size_t)B_ * H_ * N_ * 64;   // 4,194,304 floats = 16 MB
    float* qb  = ws;
    float* kb  = ws + SZ;
    float* vb  = ws + 2 * SZ;
    float* att = ws + 3 * SZ;                      // [8192, 512] row-major
    float* out = (float*)d_out;

    const dim3 gg(M_ / 128, D_ / 64);              // (64, 8)
    gemm_bt<1><<<gg, 256, 0, stream>>>(x, Wq, nullptr, qb);
    gemm_bt<1><<<gg, 256, 0, stream>>>(x, Wk, nullptr, kb);
    gemm_bt<1><<<gg, 256, 0, stream>>>(x, Wv, nullptr, vb);

    attn_fwd<<<dim3(N_ / 64, B_ * H_), 256, 0, stream>>>(qb, kb, vb, att);

    gemm_bt<0><<<gg, 256, 0, stream>>>(att, Wo, bo, out);
}

// Round 2
// 699.053 us; speedup vs baseline: 5.8177x; 5.8177x over previous
//
#include <hip/hip_runtime.h>
#include <hip/hip_bf16.h>

#define B_ 2
#define N_ 4096
#define D_ 512
#define H_ 8
#define M_ (B_*N_)      // 8192 rows
#define SCALE_ 0.125f   // 64^-0.5

typedef short bf16x8 __attribute__((ext_vector_type(8)));
typedef float f32x4  __attribute__((ext_vector_type(4)));

static __device__ __forceinline__ unsigned short f2bf(float f) {
    union { float f; unsigned int u; } v; v.f = f;
    unsigned int r = v.u + 0x7fffu + ((v.u >> 16) & 1u);   // RNE
    return (unsigned short)(r >> 16);
}
static __device__ __forceinline__ float bf2f(unsigned short h) {
    union { unsigned int u; float f; } v; v.u = ((unsigned int)h) << 16;
    return v.f;
}

// ---------------------------------------------------------------------------
// GEMM: Y = A @ W^T (+bias). A[M_,512] fp32 row-major, W[512,512] row-major.
// MODE 0: fp32 out[i*512+j] + bias[j]                       (final projection)
// MODE 1: split-bf16 hi/lo -> [bh][n][64], value*scale      (q with 0.125, k with 1)
// MODE 3: split-bf16 hi/lo TRANSPOSED -> [bh][64 d][4096 n] (v for PV B-operand)
// ---------------------------------------------------------------------------
template<int MODE>
__global__ __launch_bounds__(256) void gemm_bt(const float* __restrict__ A,
                                               const float* __restrict__ W,
                                               const float* __restrict__ bias,
                                               float* __restrict__ outF,
                                               unsigned short* __restrict__ outHi,
                                               unsigned short* __restrict__ outLo,
                                               float scale)
{
    __shared__ float As[16][132];
    __shared__ float Bs[16][68];

    const int t  = threadIdx.x;
    const int tx = t & 15;
    const int ty = t >> 4;
    const int rowBase = blockIdx.x * 128;
    const int colBase = blockIdx.y * 64;

    float acc[8][4];
#pragma unroll
    for (int i = 0; i < 8; ++i)
#pragma unroll
        for (int j = 0; j < 4; ++j) acc[i][j] = 0.f;

    const int ar = t >> 2;
    const int ac = (t & 3) * 4;

    for (int k0 = 0; k0 < 512; k0 += 16) {
        float4 a0 = *(const float4*)&A[(size_t)(rowBase + ar) * 512 + k0 + ac];
        float4 a1 = *(const float4*)&A[(size_t)(rowBase + ar + 64) * 512 + k0 + ac];
        float4 b0 = *(const float4*)&W[(size_t)(colBase + ar) * 512 + k0 + ac];
        As[ac + 0][ar] = a0.x; As[ac + 1][ar] = a0.y; As[ac + 2][ar] = a0.z; As[ac + 3][ar] = a0.w;
        As[ac + 0][ar + 64] = a1.x; As[ac + 1][ar + 64] = a1.y; As[ac + 2][ar + 64] = a1.z; As[ac + 3][ar + 64] = a1.w;
        Bs[ac + 0][ar] = b0.x; Bs[ac + 1][ar] = b0.y; Bs[ac + 2][ar] = b0.z; Bs[ac + 3][ar] = b0.w;
        __syncthreads();

#pragma unroll
        for (int kk = 0; kk < 16; ++kk) {
            float4 av0 = *(const float4*)&As[kk][ty * 8];
            float4 av1 = *(const float4*)&As[kk][ty * 8 + 4];
            float4 bv  = *(const float4*)&Bs[kk][tx * 4];
            float aa[8] = {av0.x, av0.y, av0.z, av0.w, av1.x, av1.y, av1.z, av1.w};
            float bb[4] = {bv.x, bv.y, bv.z, bv.w};
#pragma unroll
            for (int i = 0; i < 8; ++i)
#pragma unroll
                for (int j = 0; j < 4; ++j)
                    acc[i][j] = fmaf(aa[i], bb[j], acc[i][j]);
        }
        __syncthreads();
    }

    const int j0 = colBase + tx * 4;
    if (MODE == 0) {
#pragma unroll
        for (int i = 0; i < 8; ++i) {
            const int gi = rowBase + ty * 8 + i;
            float4 r = make_float4(acc[i][0], acc[i][1], acc[i][2], acc[i][3]);
            float4 bv = *(const float4*)&bias[j0];
            r.x += bv.x; r.y += bv.y; r.z += bv.z; r.w += bv.w;
            *(float4*)&outF[(size_t)gi * 512 + j0] = r;
        }
    } else if (MODE == 1) {
        const int h = j0 >> 6, d0 = j0 & 63;
#pragma unroll
        for (int i = 0; i < 8; ++i) {
            const int gi = rowBase + ty * 8 + i;
            const int b = gi >> 12, n = gi & (N_ - 1);
            const size_t base = ((size_t)(b * H_ + h) * N_ + n) * 64 + d0;
            ushort4 hv, lv;
            float s0 = acc[i][0] * scale, s1 = acc[i][1] * scale,
                  s2 = acc[i][2] * scale, s3 = acc[i][3] * scale;
            hv.x = f2bf(s0); hv.y = f2bf(s1); hv.z = f2bf(s2); hv.w = f2bf(s3);
            lv.x = f2bf(s0 - bf2f(hv.x)); lv.y = f2bf(s1 - bf2f(hv.y));
            lv.z = f2bf(s2 - bf2f(hv.z)); lv.w = f2bf(s3 - bf2f(hv.w));
            *(ushort4*)&outHi[base] = hv;
            *(ushort4*)&outLo[base] = lv;
        }
    } else {  // MODE 3: transposed V
        const int gi0 = rowBase + ty * 8;
        const int b = gi0 >> 12, n0 = gi0 & (N_ - 1);
        const int h = j0 >> 6, d0 = j0 & 63;
#pragma unroll
        for (int dj = 0; dj < 4; ++dj) {
            bf16x8 hv, lv;
#pragma unroll
            for (int i = 0; i < 8; ++i) {
                float s = acc[i][dj];
                unsigned short hh = f2bf(s);
                hv[i] = (short)hh;
                lv[i] = (short)f2bf(s - bf2f(hh));
            }
            const size_t base = ((size_t)(b * H_ + h) * 64 + d0 + dj) * N_ + n0;
            *(bf16x8*)&outHi[base] = hv;
            *(bf16x8*)&outLo[base] = lv;
        }
    }
}

// ---------------------------------------------------------------------------
// Flash attention, split-bf16 MFMA (16x16x32). Block = 256 thr = 4 waves.
// Wave owns 32 Q rows (2 row-tiles of 16); KBLK = 64. fp32-level accuracy via
// 3-term split: hi*hi + hi*lo + lo*hi for QK^T and P*V.
// LDS K/V/P tiles XOR-swizzled (16B-chunk ^ (row&7)) to kill the 128B-stride
// 16-way bank conflict on ds_read_b128.
// ---------------------------------------------------------------------------
__global__ __launch_bounds__(256, 2) void attn_mfma(
    const unsigned short* __restrict__ qh, const unsigned short* __restrict__ ql,
    const unsigned short* __restrict__ kh, const unsigned short* __restrict__ kl,
    const unsigned short* __restrict__ vth, const unsigned short* __restrict__ vtl,
    float* __restrict__ o)
{
    __shared__ unsigned short Ks[2][4096];     // [plane][row*64 + swz col], rows = K rows
    __shared__ unsigned short Vs[2][4096];     // rows = d index (V transposed)
    __shared__ unsigned short Ps[4][2][2056];  // per-wave P hi/lo, +8 pad per plane

    const int t    = threadIdx.x;
    const int wave = t >> 6;
    const int lane = t & 63;
    const int l15  = lane & 15;
    const int g    = lane >> 4;               // 0..3
    const int bh   = blockIdx.y;
    const int qbase = blockIdx.x * 128 + wave * 32;

    // Q fragments (A-operand), held in registers for the whole kernel.
    // A-frag: lane holds A[l15][g*8 + i] per 32-wide k-chunk c.
    bf16x8 qf[2][2][2];   // [rowtile][chunk][hi/lo]
#pragma unroll
    for (int rt = 0; rt < 2; ++rt)
#pragma unroll
        for (int c = 0; c < 2; ++c) {
            const size_t src = ((size_t)bh * N_ + qbase + rt * 16 + l15) * 64 + c * 32 + g * 8;
            qf[rt][c][0] = *(const bf16x8*)&qh[src];
            qf[rt][c][1] = *(const bf16x8*)&ql[src];
        }

    f32x4 O[2][4];        // [rowtile][dtile]
#pragma unroll
    for (int rt = 0; rt < 2; ++rt)
#pragma unroll
        for (int dt = 0; dt < 4; ++dt) O[rt][dt] = (f32x4){0.f, 0.f, 0.f, 0.f};
    float mreg[8], lreg[8];
#pragma unroll
    for (int i = 0; i < 8; ++i) { mreg[i] = -3.0e38f; lreg[i] = 0.f; }

    for (int kt = 0; kt < N_ / 64; ++kt) {
        // ---- stage K hi/lo + Vt hi/lo (8KB each) with swizzled ds writes ----
#pragma unroll
        for (int p = 0; p < 2; ++p) {
            const int flat = t + p * 256;
            const int row = flat >> 3, c16 = flat & 7;
            const int dst = row * 64 + ((c16 ^ (row & 7)) * 8);
            const size_t gK = ((size_t)bh * N_ + kt * 64 + row) * 64 + c16 * 8;
            const size_t gV = ((size_t)bh * 64 + row) * N_ + kt * 64 + c16 * 8;
            *(bf16x8*)&Ks[0][dst] = *(const bf16x8*)&kh[gK];
            *(bf16x8*)&Ks[1][dst] = *(const bf16x8*)&kl[gK];
            *(bf16x8*)&Vs[0][dst] = *(const bf16x8*)&vth[gV];
            *(bf16x8*)&Vs[1][dst] = *(const bf16x8*)&vtl[gV];
        }
        __syncthreads();

        // ---- QK^T: S[rt][j] = Q(32xd64) . K^T, split 3-term ----
        f32x4 S[2][4];
#pragma unroll
        for (int rt = 0; rt < 2; ++rt)
#pragma unroll
            for (int j = 0; j < 4; ++j) S[rt][j] = (f32x4){0.f, 0.f, 0.f, 0.f};

#pragma unroll
        for (int j = 0; j < 4; ++j) {
#pragma unroll
            for (int c = 0; c < 2; ++c) {
                const int krow = j * 16 + l15;
                const int off = krow * 64 + (((c * 4 + g) ^ (krow & 7)) * 8);
                bf16x8 kfh = *(const bf16x8*)&Ks[0][off];
                bf16x8 kfl = *(const bf16x8*)&Ks[1][off];
#pragma unroll
                for (int rt = 0; rt < 2; ++rt) {
                    S[rt][j] = __builtin_amdgcn_mfma_f32_16x16x32_bf16(qf[rt][c][0], kfh, S[rt][j], 0, 0, 0);
                    S[rt][j] = __builtin_amdgcn_mfma_f32_16x16x32_bf16(qf[rt][c][0], kfl, S[rt][j], 0, 0, 0);
                    S[rt][j] = __builtin_amdgcn_mfma_f32_16x16x32_bf16(qf[rt][c][1], kfh, S[rt][j], 0, 0, 0);
                }
            }
        }

        // ---- online softmax (rows live in 16-lane groups) + P -> LDS ----
#pragma unroll
        for (int rt = 0; rt < 2; ++rt) {
#pragma unroll
            for (int r = 0; r < 4; ++r) {
                const int row = rt * 16 + g * 4 + r;
                const int mi = rt * 4 + r;
                float smax = fmaxf(fmaxf(S[rt][0][r], S[rt][1][r]), fmaxf(S[rt][2][r], S[rt][3][r]));
                smax = fmaxf(smax, __shfl_xor(smax, 1));
                smax = fmaxf(smax, __shfl_xor(smax, 2));
                smax = fmaxf(smax, __shfl_xor(smax, 4));
                smax = fmaxf(smax, __shfl_xor(smax, 8));
                const float mnew = fmaxf(mreg[mi], smax);
                const float alpha = __expf(mreg[mi] - mnew);
                mreg[mi] = mnew;
                float lsum = 0.f;
#pragma unroll
                for (int j = 0; j < 4; ++j) {
                    const float p = __expf(S[rt][j][r] - mnew);
                    lsum += p;
                    const unsigned short ph = f2bf(p);
                    const unsigned short pl = f2bf(p - bf2f(ph));
                    const unsigned short oph = (unsigned short)__shfl_xor((int)ph, 1);
                    const unsigned short opl = (unsigned short)__shfl_xor((int)pl, 1);
                    const int col = j * 16 + l15;
                    if ((l15 & 1) == 0) {
                        const unsigned int wd = (unsigned int)ph | ((unsigned int)oph << 16);
                        const int e = row * 64 + (col ^ ((row & 7) << 3));
                        *(unsigned int*)&Ps[wave][0][e] = wd;
                    } else {
                        const unsigned int wd = (unsigned int)opl | ((unsigned int)pl << 16);
                        const int e = row * 64 + ((col - 1) ^ ((row & 7) << 3));
                        *(unsigned int*)&Ps[wave][1][e] = wd;
                    }
                }
                lreg[mi] = lreg[mi] * alpha + lsum;
#pragma unroll
                for (int dt = 0; dt < 4; ++dt) O[rt][dt][r] *= alpha;
            }
        }
        // P writes are intra-wave producer->consumer: drain LDS queue.
        asm volatile("s_waitcnt lgkmcnt(0)" ::: "memory");

        // ---- PV: O[rt][dt] += P(16x64) . V(64x64), split 3-term ----
#pragma unroll
        for (int kc = 0; kc < 2; ++kc) {
            bf16x8 pa[2][2];
#pragma unroll
            for (int rt = 0; rt < 2; ++rt) {
                const int prow = rt * 16 + l15;
                const int pe = prow * 64 + ((kc * 32 + g * 8) ^ ((prow & 7) << 3));
                pa[rt][0] = *(const bf16x8*)&Ps[wave][0][pe];
                pa[rt][1] = *(const bf16x8*)&Ps[wave][1][pe];
            }
#pragma unroll
            for (int dt = 0; dt < 4; ++dt) {
                const int vrow = dt * 16 + l15;
                const int ve = vrow * 64 + (((kc * 4 + g) ^ (vrow & 7)) * 8);
                bf16x8 vfh = *(const bf16x8*)&Vs[0][ve];
                bf16x8 vfl = *(const bf16x8*)&Vs[1][ve];
#pragma unroll
                for (int rt = 0; rt < 2; ++rt) {
                    O[rt][dt] = __builtin_amdgcn_mfma_f32_16x16x32_bf16(pa[rt][0], vfh, O[rt][dt], 0, 0, 0);
                    O[rt][dt] = __builtin_amdgcn_mfma_f32_16x16x32_bf16(pa[rt][0], vfl, O[rt][dt], 0, 0, 0);
                    O[rt][dt] = __builtin_amdgcn_mfma_f32_16x16x32_bf16(pa[rt][1], vfh, O[rt][dt], 0, 0, 0);
                }
            }
        }
        __syncthreads();
    }

    // ---- epilogue: normalize and write [b, n, h*64+d] fp32 ----
    const int b = bh >> 3, h = bh & 7;
    float linv[8];
#pragma unroll
    for (int mi = 0; mi < 8; ++mi) {
        float lt = lreg[mi];
        lt += __shfl_xor(lt, 1);
        lt += __shfl_xor(lt, 2);
        lt += __shfl_xor(lt, 4);
        lt += __shfl_xor(lt, 8);
        linv[mi] = 1.0f / lt;
    }
#pragma unroll
    for (int rt = 0; rt < 2; ++rt)
#pragma unroll
        for (int dt = 0; dt < 4; ++dt)
#pragma unroll
            for (int r = 0; r < 4; ++r) {
                const int n = qbase + rt * 16 + g * 4 + r;
                o[((size_t)(b * N_) + n) * 512 + h * 64 + dt * 16 + l15] =
                    O[rt][dt][r] * linv[rt * 4 + r];
            }
}

// ---------------------------------------------------------------------------
extern "C" void kernel_launch(void* const* d_in, const int* in_sizes, int n_in,
                              void* d_out, int out_size, void* d_ws, size_t ws_size,
                              hipStream_t stream)
{
    const float* x  = (const float*)d_in[0];
    const float* Wq = (const float*)d_in[1];
    const float* Wk = (const float*)d_in[2];
    const float* Wv = (const float*)d_in[3];
    const float* Wo = (const float*)d_in[4];
    const float* bo = (const float*)d_in[5];

    unsigned char* w8 = (unsigned char*)d_ws;
    const size_t SEG = (size_t)16 * N_ * 64 * 2;   // 8 MB per bf16 array
    unsigned short* qhi = (unsigned short*)(w8 + 0 * SEG);
    unsigned short* qlo = (unsigned short*)(w8 + 1 * SEG);
    unsigned short* khi = (unsigned short*)(w8 + 2 * SEG);
    unsigned short* klo = (unsigned short*)(w8 + 3 * SEG);
    unsigned short* vth = (unsigned short*)(w8 + 4 * SEG);
    unsigned short* vtl = (unsigned short*)(w8 + 5 * SEG);
    float*          att = (float*)(w8 + 6 * SEG);  // 16 MB fp32 [8192][512]
    float* out = (float*)d_out;

    const dim3 gg(M_ / 128, D_ / 64);              // (64, 8)
    gemm_bt<1><<<gg, 256, 0, stream>>>(x, Wq, nullptr, nullptr, qhi, qlo, SCALE_);
    gemm_bt<1><<<gg, 256, 0, stream>>>(x, Wk, nullptr, nullptr, khi, klo, 1.0f);
    gemm_bt<3><<<gg, 256, 0, stream>>>(x, Wv, nullptr, nullptr, vth, vtl, 1.0f);

    attn_mfma<<<dim3(N_ / 128, 16), 256, 0, stream>>>(qhi, qlo, khi, klo, vth, vtl, att);

    gemm_bt<0><<<gg, 256, 0, stream>>>(att, Wo, bo, out, nullptr, nullptr, 1.0f);
}

// Round 4
// 529.792 us; speedup vs baseline: 7.6763x; 1.3195x over previous
//
#include <hip/hip_runtime.h>
#include <hip/hip_bf16.h>

#define B_ 2
#define N_ 4096
#define D_ 512
#define H_ 8
#define M_ (B_*N_)              // 8192 rows
#define QSCALE_ 0.18033688011f  // 0.125 * log2(e): softmax runs in log2 domain

typedef short bf16x8 __attribute__((ext_vector_type(8)));
typedef float f32x4  __attribute__((ext_vector_type(4)));

static __device__ __forceinline__ unsigned short f2bf(float f) {
    union { float f; unsigned int u; } v; v.f = f;
    unsigned int r = v.u + 0x7fffu + ((v.u >> 16) & 1u);   // RNE
    return (unsigned short)(r >> 16);
}
static __device__ __forceinline__ float bf2f(unsigned short h) {
    union { unsigned int u; float f; } v; v.u = ((unsigned int)h) << 16;
    return v.f;
}
static __device__ __forceinline__ unsigned int cvt_pk_bf16(float a, float b) {
    unsigned int r;  // D[15:0]=bf16(a), D[31:16]=bf16(b)
    asm("v_cvt_pk_bf16_f32 %0, %1, %2" : "=v"(r) : "v"(a), "v"(b));
    return r;
}
static __device__ __forceinline__ float lo_bf(unsigned int w) {   // f32 of D[15:0]
    return __uint_as_float(w << 16);
}
static __device__ __forceinline__ float hi_bf(unsigned int w) {   // f32 of D[31:16]
    return __uint_as_float(w & 0xffff0000u);
}

// ---------------------------------------------------------------------------
// GEMM: Y = A @ W^T (+bias). A[M_,512] fp32 row-major, W[512,512] row-major.
// MODE 0: fp32 out[i*512+j] + bias[j]                       (final projection)
// MODE 1: split-bf16 hi/lo -> [bh][n][64], value*scale      (q w/ 0.125*log2e, k w/ 1)
// MODE 3: split-bf16 hi/lo TRANSPOSED -> [bh][64 d][4096 n] (v for PV A-operand)
// ---------------------------------------------------------------------------
template<int MODE>
__global__ __launch_bounds__(256) void gemm_bt(const float* __restrict__ A,
                                               const float* __restrict__ W,
                                               const float* __restrict__ bias,
                                               float* __restrict__ outF,
                                               unsigned short* __restrict__ outHi,
                                               unsigned short* __restrict__ outLo,
                                               float scale)
{
    __shared__ float As[16][132];
    __shared__ float Bs[16][68];

    const int t  = threadIdx.x;
    const int tx = t & 15;
    const int ty = t >> 4;
    const int rowBase = blockIdx.x * 128;
    const int colBase = blockIdx.y * 64;

    float acc[8][4];
#pragma unroll
    for (int i = 0; i < 8; ++i)
#pragma unroll
        for (int j = 0; j < 4; ++j) acc[i][j] = 0.f;

    const int ar = t >> 2;
    const int ac = (t & 3) * 4;

    for (int k0 = 0; k0 < 512; k0 += 16) {
        float4 a0 = *(const float4*)&A[(size_t)(rowBase + ar) * 512 + k0 + ac];
        float4 a1 = *(const float4*)&A[(size_t)(rowBase + ar + 64) * 512 + k0 + ac];
        float4 b0 = *(const float4*)&W[(size_t)(colBase + ar) * 512 + k0 + ac];
        As[ac + 0][ar] = a0.x; As[ac + 1][ar] = a0.y; As[ac + 2][ar] = a0.z; As[ac + 3][ar] = a0.w;
        As[ac + 0][ar + 64] = a1.x; As[ac + 1][ar + 64] = a1.y; As[ac + 2][ar + 64] = a1.z; As[ac + 3][ar + 64] = a1.w;
        Bs[ac + 0][ar] = b0.x; Bs[ac + 1][ar] = b0.y; Bs[ac + 2][ar] = b0.z; Bs[ac + 3][ar] = b0.w;
        __syncthreads();

#pragma unroll
        for (int kk = 0; kk < 16; ++kk) {
            float4 av0 = *(const float4*)&As[kk][ty * 8];
            float4 av1 = *(const float4*)&As[kk][ty * 8 + 4];
            float4 bv  = *(const float4*)&Bs[kk][tx * 4];
            float aa[8] = {av0.x, av0.y, av0.z, av0.w, av1.x, av1.y, av1.z, av1.w};
            float bb[4] = {bv.x, bv.y, bv.z, bv.w};
#pragma unroll
            for (int i = 0; i < 8; ++i)
#pragma unroll
                for (int j = 0; j < 4; ++j)
                    acc[i][j] = fmaf(aa[i], bb[j], acc[i][j]);
        }
        __syncthreads();
    }

    const int j0 = colBase + tx * 4;
    if (MODE == 0) {
#pragma unroll
        for (int i = 0; i < 8; ++i) {
            const int gi = rowBase + ty * 8 + i;
            float4 r = make_float4(acc[i][0], acc[i][1], acc[i][2], acc[i][3]);
            float4 bv = *(const float4*)&bias[j0];
            r.x += bv.x; r.y += bv.y; r.z += bv.z; r.w += bv.w;
            *(float4*)&outF[(size_t)gi * 512 + j0] = r;
        }
    } else if (MODE == 1) {
        const int h = j0 >> 6, d0 = j0 & 63;
#pragma unroll
        for (int i = 0; i < 8; ++i) {
            const int gi = rowBase + ty * 8 + i;
            const int b = gi >> 12, n = gi & (N_ - 1);
            const size_t base = ((size_t)(b * H_ + h) * N_ + n) * 64 + d0;
            ushort4 hv, lv;
            float s0 = acc[i][0] * scale, s1 = acc[i][1] * scale,
                  s2 = acc[i][2] * scale, s3 = acc[i][3] * scale;
            hv.x = f2bf(s0); hv.y = f2bf(s1); hv.z = f2bf(s2); hv.w = f2bf(s3);
            lv.x = f2bf(s0 - bf2f(hv.x)); lv.y = f2bf(s1 - bf2f(hv.y));
            lv.z = f2bf(s2 - bf2f(hv.z)); lv.w = f2bf(s3 - bf2f(hv.w));
            *(ushort4*)&outHi[base] = hv;
            *(ushort4*)&outLo[base] = lv;
        }
    } else {  // MODE 3: transposed V
        const int gi0 = rowBase + ty * 8;
        const int b = gi0 >> 12, n0 = gi0 & (N_ - 1);
        const int h = j0 >> 6, d0 = j0 & 63;
#pragma unroll
        for (int dj = 0; dj < 4; ++dj) {
            bf16x8 hv, lv;
#pragma unroll
            for (int i = 0; i < 8; ++i) {
                float s = acc[i][dj];
                unsigned short hh = f2bf(s);
                hv[i] = (short)hh;
                lv[i] = (short)f2bf(s - bf2f(hh));
            }
            const size_t base = ((size_t)(b * H_ + h) * 64 + d0 + dj) * N_ + n0;
            *(bf16x8*)&outHi[base] = hv;
            *(bf16x8*)&outLo[base] = lv;
        }
    }
}

// ---------------------------------------------------------------------------
// Flash attention, split-bf16 MFMA 16x16x32, swapped-operand form.
//
// KEY TRICK (fixes round-3's bpermute bug by removing the redistribution):
// K is staged into LDS with PERMUTED rows  rho(n) = 32*(n>>5) + 16*((n>>2)&1)
// + 4*((n>>3)&3) + (n&3), so the S^T = mfma(K,Q) output hands lane (l15,g),
// tile j, reg r the score for PHYSICAL k-row n = 32*(j>>1) + 8g + 4*(j&1) + r.
// That is exactly PV's B-fragment layout: P^T fragments are built lane-locally
// with cvt_pk (no bpermute, no P LDS). Softmax stats: lane-local 16-max/sum +
// shfl_xor(16,32) over the 4 g-lanes. O^T = mfma(V^T, P^T): alpha and 1/l are
// lane-uniform (qrow = l15). K/V double-buffered (64 KB), loads issued before
// compute (T14). T13 defer-max (thr=8 in log2 domain).
// 3-term split: Kh*Qh + Kl*Qh + Kh*Ql ; Vh*Ph + Vl*Ph + Vh*Pl.
// ---------------------------------------------------------------------------
__global__ __launch_bounds__(256, 2) void attn_mfma(
    const unsigned short* __restrict__ qh, const unsigned short* __restrict__ ql,
    const unsigned short* __restrict__ kh, const unsigned short* __restrict__ kl,
    const unsigned short* __restrict__ vth, const unsigned short* __restrict__ vtl,
    float* __restrict__ o)
{
    __shared__ unsigned short Kb[2][2][4096];   // [buf][hi/lo][lds_row*64 + swz col]
    __shared__ unsigned short Vb[2][2][4096];   // rows = d (V transposed), linear

    const int t    = threadIdx.x;
    const int lane = t & 63;
    const int wave = t >> 6;
    const int l15  = lane & 15;
    const int g    = lane >> 4;
    const int bh   = blockIdx.y;
    const int qbase = blockIdx.x * 128 + wave * 32;

    // Q B-fragments: lane(l15,g) holds Q[qrow=rt*16+l15][d = c*32+g*8+i]
    bf16x8 qf[2][2][2];   // [rowtile][chunk][hi/lo]
#pragma unroll
    for (int rt = 0; rt < 2; ++rt)
#pragma unroll
        for (int c = 0; c < 2; ++c) {
            const size_t src = ((size_t)bh * N_ + qbase + rt * 16 + l15) * 64 + c * 32 + g * 8;
            qf[rt][c][0] = *(const bf16x8*)&qh[src];
            qf[rt][c][1] = *(const bf16x8*)&ql[src];
        }

    f32x4 O[2][4];        // O^T: [rowtile][dtile], lane holds qrow=l15, d=dt*16+g*4+r
#pragma unroll
    for (int rt = 0; rt < 2; ++rt)
#pragma unroll
        for (int dt = 0; dt < 4; ++dt) O[rt][dt] = (f32x4){0.f, 0.f, 0.f, 0.f};
    float mreg[2] = {-3.0e38f, -3.0e38f};
    float lreg[2] = {0.f, 0.f};

    // staging addresses: physical rows srow, srow+32; 8 lanes x 8 bf16 per row
    const int srow = t >> 3;          // 0..31
    const int sc16 = t & 7;
    const size_t kbase = (size_t)bh * N_ * 64;
    const size_t vbase = (size_t)bh * 64 * N_;
    // V: linear dest rows
    const int vdst0 = srow * 64 + ((sc16 ^ (srow & 7)) * 8);
    const int vdst1 = (srow + 32) * 64 + ((sc16 ^ ((srow + 32) & 7)) * 8);
    // K: permuted dest rows rho(n); rho(n+32) = rho(n)+32
    const int krho  = (((srow >> 2) & 1) << 4) | (((srow >> 3) & 3) << 2) | (srow & 3);
    const int kdst0 = krho * 64 + ((sc16 ^ (krho & 7)) * 8);
    const int kdst1 = kdst0 + 32 * 64;   // (krho+32)&7 == krho&7

    bf16x8 sKh[2], sKl[2], sVh[2], sVl[2];

#define LOADT(KT) do {                                                          \
        const size_t gK0 = kbase + ((size_t)((KT) * 64 + srow)) * 64 + sc16 * 8;      \
        const size_t gK1 = kbase + ((size_t)((KT) * 64 + srow + 32)) * 64 + sc16 * 8; \
        const size_t gV0 = vbase + (size_t)srow * N_ + (KT) * 64 + sc16 * 8;          \
        const size_t gV1 = vbase + (size_t)(srow + 32) * N_ + (KT) * 64 + sc16 * 8;   \
        sKh[0] = *(const bf16x8*)&kh[gK0];  sKh[1] = *(const bf16x8*)&kh[gK1];  \
        sKl[0] = *(const bf16x8*)&kl[gK0];  sKl[1] = *(const bf16x8*)&kl[gK1];  \
        sVh[0] = *(const bf16x8*)&vth[gV0]; sVh[1] = *(const bf16x8*)&vth[gV1]; \
        sVl[0] = *(const bf16x8*)&vtl[gV0]; sVl[1] = *(const bf16x8*)&vtl[gV1]; \
    } while (0)

#define WRITET(BB) do {                                                         \
        *(bf16x8*)&Kb[BB][0][kdst0] = sKh[0]; *(bf16x8*)&Kb[BB][0][kdst1] = sKh[1]; \
        *(bf16x8*)&Kb[BB][1][kdst0] = sKl[0]; *(bf16x8*)&Kb[BB][1][kdst1] = sKl[1]; \
        *(bf16x8*)&Vb[BB][0][vdst0] = sVh[0]; *(bf16x8*)&Vb[BB][0][vdst1] = sVh[1]; \
        *(bf16x8*)&Vb[BB][1][vdst0] = sVl[0]; *(bf16x8*)&Vb[BB][1][vdst1] = sVl[1]; \
    } while (0)

    LOADT(0);
    WRITET(0);
    __syncthreads();

    int cur = 0;
    for (int kt = 0; kt < N_ / 64; ++kt) {
        const bool pf = (kt + 1 < N_ / 64);
        if (pf) LOADT(kt + 1);      // issue next tile's loads under this tile's compute

        // ---- QK^T (swapped): A = K rows (permuted-staged) from LDS, B = Q regs ----
        f32x4 S[2][4];
#pragma unroll
        for (int rt = 0; rt < 2; ++rt)
#pragma unroll
            for (int j = 0; j < 4; ++j) S[rt][j] = (f32x4){0.f, 0.f, 0.f, 0.f};

#pragma unroll
        for (int j = 0; j < 4; ++j) {
            const int krow = j * 16 + l15;                 // LDS row (permuted space)
            const int rb = krow * 64, sw = (krow & 7) * 8;
#pragma unroll
            for (int c = 0; c < 2; ++c) {
                const int off = rb + (((c * 4 + g) * 8) ^ sw);
                bf16x8 kfh = *(const bf16x8*)&Kb[cur][0][off];
                bf16x8 kfl = *(const bf16x8*)&Kb[cur][1][off];
#pragma unroll
                for (int rt = 0; rt < 2; ++rt) {
                    S[rt][j] = __builtin_amdgcn_mfma_f32_16x16x32_bf16(kfh, qf[rt][c][0], S[rt][j], 0, 0, 0);
                    S[rt][j] = __builtin_amdgcn_mfma_f32_16x16x32_bf16(kfl, qf[rt][c][0], S[rt][j], 0, 0, 0);
                    S[rt][j] = __builtin_amdgcn_mfma_f32_16x16x32_bf16(kfh, qf[rt][c][1], S[rt][j], 0, 0, 0);
                }
            }
        }

        // ---- in-register softmax (log2 domain) + lane-local P pack ----
        bf16x8 pah[2][2], pal[2][2];
#pragma unroll
        for (int rt = 0; rt < 2; ++rt) {
            float pmax = -3.0e38f;
#pragma unroll
            for (int j = 0; j < 4; ++j)
#pragma unroll
                for (int r = 0; r < 4; ++r) pmax = fmaxf(pmax, S[rt][j][r]);
            pmax = fmaxf(pmax, __shfl_xor(pmax, 16));
            pmax = fmaxf(pmax, __shfl_xor(pmax, 32));

            const float mold = mreg[rt];
            if (!__all(pmax <= mold + 8.0f)) {       // T13 defer-max
                const float mnew = fmaxf(mold, pmax);
                const float alpha = exp2f(mold - mnew);
#pragma unroll
                for (int dt = 0; dt < 4; ++dt)
#pragma unroll
                    for (int r = 0; r < 4; ++r) O[rt][dt][r] *= alpha;
                lreg[rt] *= alpha;
                mreg[rt] = mnew;
            }
            const float mb = mreg[rt];

            float lsum = 0.f;
#pragma unroll
            for (int j = 0; j < 4; ++j)
#pragma unroll
                for (int r = 0; r < 4; ++r) {
                    S[rt][j][r] = exp2f(S[rt][j][r] - mb);
                    lsum += S[rt][j][r];
                }
            lreg[rt] += lsum;

            // Lane-local B-frag pack: v[i] = P[n = c*32 + g*8 + i], where
            // i = 4*(j&1) + r  ->  u[0]={j=2c,r01} u[1]={2c,r23} u[2]={2c+1,r01} u[3]={2c+1,r23}
#pragma unroll
            for (int c = 0; c < 2; ++c) {
                const f32x4 s0 = S[rt][2 * c], s1 = S[rt][2 * c + 1];
                union { unsigned int u[4]; bf16x8 v; } th, tl;
                th.u[0] = cvt_pk_bf16(s0[0], s0[1]);
                th.u[1] = cvt_pk_bf16(s0[2], s0[3]);
                th.u[2] = cvt_pk_bf16(s1[0], s1[1]);
                th.u[3] = cvt_pk_bf16(s1[2], s1[3]);
                tl.u[0] = cvt_pk_bf16(s0[0] - lo_bf(th.u[0]), s0[1] - hi_bf(th.u[0]));
                tl.u[1] = cvt_pk_bf16(s0[2] - lo_bf(th.u[1]), s0[3] - hi_bf(th.u[1]));
                tl.u[2] = cvt_pk_bf16(s1[0] - lo_bf(th.u[2]), s1[1] - hi_bf(th.u[2]));
                tl.u[3] = cvt_pk_bf16(s1[2] - lo_bf(th.u[3]), s1[3] - hi_bf(th.u[3]));
                pah[rt][c] = th.v;
                pal[rt][c] = tl.v;
            }
        }

        // ---- PV (swapped): O^T += V^T . P^T ----
#pragma unroll
        for (int c = 0; c < 2; ++c) {
#pragma unroll
            for (int dt = 0; dt < 4; ++dt) {
                const int vrow = dt * 16 + l15;
                const int off = vrow * 64 + (((c * 4 + g) * 8) ^ ((vrow & 7) * 8));
                bf16x8 vfh = *(const bf16x8*)&Vb[cur][0][off];
                bf16x8 vfl = *(const bf16x8*)&Vb[cur][1][off];
#pragma unroll
                for (int rt = 0; rt < 2; ++rt) {
                    O[rt][dt] = __builtin_amdgcn_mfma_f32_16x16x32_bf16(vfh, pah[rt][c], O[rt][dt], 0, 0, 0);
                    O[rt][dt] = __builtin_amdgcn_mfma_f32_16x16x32_bf16(vfl, pah[rt][c], O[rt][dt], 0, 0, 0);
                    O[rt][dt] = __builtin_amdgcn_mfma_f32_16x16x32_bf16(vfh, pal[rt][c], O[rt][dt], 0, 0, 0);
                }
            }
        }

        if (pf) WRITET(cur ^ 1);    // compiler inserts vmcnt waits on staging regs
        __syncthreads();
        cur ^= 1;
    }

    // ---- epilogue: 1/l is lane-uniform per q-row (= l15) ----
    const int b = bh >> 3, hh = bh & 7;
#pragma unroll
    for (int rt = 0; rt < 2; ++rt) {
        float lt = lreg[rt];
        lt += __shfl_xor(lt, 16);
        lt += __shfl_xor(lt, 32);
        const float inv = 1.0f / lt;
        const int n = qbase + rt * 16 + l15;
        float* dst = &o[((size_t)(b * N_) + n) * 512 + hh * 64 + g * 4];
#pragma unroll
        for (int dt = 0; dt < 4; ++dt) {
            float4 w = make_float4(O[rt][dt][0] * inv, O[rt][dt][1] * inv,
                                   O[rt][dt][2] * inv, O[rt][dt][3] * inv);
            *(float4*)&dst[dt * 16] = w;
        }
    }
#undef LOADT
#undef WRITET
}

// ---------------------------------------------------------------------------
extern "C" void kernel_launch(void* const* d_in, const int* in_sizes, int n_in,
                              void* d_out, int out_size, void* d_ws, size_t ws_size,
                              hipStream_t stream)
{
    const float* x  = (const float*)d_in[0];
    const float* Wq = (const float*)d_in[1];
    const float* Wk = (const float*)d_in[2];
    const float* Wv = (const float*)d_in[3];
    const float* Wo = (const float*)d_in[4];
    const float* bo = (const float*)d_in[5];

    unsigned char* w8 = (unsigned char*)d_ws;
    const size_t SEG = (size_t)16 * N_ * 64 * 2;   // 8 MB per bf16 array
    unsigned short* qhi = (unsigned short*)(w8 + 0 * SEG);
    unsigned short* qlo = (unsigned short*)(w8 + 1 * SEG);
    unsigned short* khi = (unsigned short*)(w8 + 2 * SEG);
    unsigned short* klo = (unsigned short*)(w8 + 3 * SEG);
    unsigned short* vth = (unsigned short*)(w8 + 4 * SEG);
    unsigned short* vtl = (unsigned short*)(w8 + 5 * SEG);
    float*          att = (float*)(w8 + 6 * SEG);  // 16 MB fp32 [8192][512]
    float* out = (float*)d_out;

    const dim3 gg(M_ / 128, D_ / 64);              // (64, 8)
    gemm_bt<1><<<gg, 256, 0, stream>>>(x, Wq, nullptr, nullptr, qhi, qlo, QSCALE_);
    gemm_bt<1><<<gg, 256, 0, stream>>>(x, Wk, nullptr, nullptr, khi, klo, 1.0f);
    gemm_bt<3><<<gg, 256, 0, stream>>>(x, Wv, nullptr, nullptr, vth, vtl, 1.0f);

    attn_mfma<<<dim3(N_ / 128, 16), 256, 0, stream>>>(qhi, qlo, khi, klo, vth, vtl, att);

    gemm_bt<0><<<gg, 256, 0, stream>>>(att, Wo, bo, out, nullptr, nullptr, 1.0f);
}

// Round 5
// 365.709 us; speedup vs baseline: 11.1205x; 1.4487x over previous
//
#include <hip/hip_runtime.h>
#include <hip/hip_bf16.h>

#define B_ 2
#define N_ 4096
#define D_ 512
#define H_ 8
#define M_ (B_*N_)              // 8192 rows
#define QSCALE_ 0.18033688011f  // 0.125 * log2(e): softmax runs in log2 domain

typedef short bf16x8 __attribute__((ext_vector_type(8)));
typedef float f32x4  __attribute__((ext_vector_type(4)));

static __device__ __forceinline__ unsigned short f2bf(float f) {
    union { float f; unsigned int u; } v; v.f = f;
    unsigned int r = v.u + 0x7fffu + ((v.u >> 16) & 1u);   // RNE
    return (unsigned short)(r >> 16);
}
static __device__ __forceinline__ float bf2f(unsigned short h) {
    union { unsigned int u; float f; } v; v.u = ((unsigned int)h) << 16;
    return v.f;
}
static __device__ __forceinline__ unsigned int cvt_pk_bf16(float a, float b) {
    unsigned int r;  // D[15:0]=bf16(a), D[31:16]=bf16(b)
    asm("v_cvt_pk_bf16_f32 %0, %1, %2" : "=v"(r) : "v"(a), "v"(b));
    return r;
}
static __device__ __forceinline__ float lo_bf(unsigned int w) { return __uint_as_float(w << 16); }
static __device__ __forceinline__ float hi_bf(unsigned int w) { return __uint_as_float(w & 0xffff0000u); }

// ---------------------------------------------------------------------------
// fp32 -> split bf16 hi/lo, grid-stride, float4/ushort4 vectorized.
// ---------------------------------------------------------------------------
__global__ void conv_split(const float* __restrict__ src, unsigned short* __restrict__ dh,
                           unsigned short* __restrict__ dl, int n4)
{
    int i = blockIdx.x * blockDim.x + threadIdx.x;
    const int stride = gridDim.x * blockDim.x;
    for (; i < n4; i += stride) {
        float4 v = ((const float4*)src)[i];
        ushort4 hv, lv;
        hv.x = f2bf(v.x); hv.y = f2bf(v.y); hv.z = f2bf(v.z); hv.w = f2bf(v.w);
        lv.x = f2bf(v.x - bf2f(hv.x)); lv.y = f2bf(v.y - bf2f(hv.y));
        lv.z = f2bf(v.z - bf2f(hv.z)); lv.w = f2bf(v.w - bf2f(hv.w));
        ((ushort4*)dh)[i] = hv;
        ((ushort4*)dl)[i] = lv;
    }
}

// 4 weight matrices (512x512 each) -> wbuf hi/lo [4][512][512]
__global__ void conv_w4(const float* __restrict__ w0, const float* __restrict__ w1,
                        const float* __restrict__ w2, const float* __restrict__ w3,
                        unsigned short* __restrict__ dh, unsigned short* __restrict__ dl)
{
    const int which = blockIdx.y;
    const float* src = which == 0 ? w0 : which == 1 ? w1 : which == 2 ? w2 : w3;
    const int i = blockIdx.x * 256 + threadIdx.x;          // 0..65535 float4s
    float4 v = ((const float4*)src)[i];
    ushort4 hv, lv;
    hv.x = f2bf(v.x); hv.y = f2bf(v.y); hv.z = f2bf(v.z); hv.w = f2bf(v.w);
    lv.x = f2bf(v.x - bf2f(hv.x)); lv.y = f2bf(v.y - bf2f(hv.y));
    lv.z = f2bf(v.z - bf2f(hv.z)); lv.w = f2bf(v.w - bf2f(hv.w));
    ((ushort4*)(dh + (size_t)which * 262144))[i] = hv;
    ((ushort4*)(dl + (size_t)which * 262144))[i] = lv;
}

// ---------------------------------------------------------------------------
// Split-bf16 MFMA GEMM: Y = A @ W^T, A[M][512] hi/lo bf16, W[512][512] hi/lo.
// 3-term: Ah*Wh + Al*Wh + Ah*Wl. Tile 128x128, BK=32, 4 waves (2x2), each
// wave 64x64 = 4x4 MFMA frags. mfma(af,wf) -> D[m = g*4+r][n = l15]
// (convention verified by the passing attn kernels).
// LDS rows: 64 ushort = [32 hi k][32 lo k], 8x16B chunks XOR-swizzled by row&7
// (same proven pattern as attn: 0 bank conflicts). Double-buffered, 64 KB.
// MODE 0: fp32 out[m][512] + bias                      (final projection)
// MODE 1: split hi/lo -> [bh][seq][64]; which=by>>2 picks (q,scale)|(k,1)
// MODE 2: split hi/lo transposed -> [bh][64][4096]     (v)
// ---------------------------------------------------------------------------
template<int MODE>
__global__ __launch_bounds__(256, 2) void gemm_mfma(
    const unsigned short* __restrict__ Ah, const unsigned short* __restrict__ Al,
    const unsigned short* __restrict__ Wh, const unsigned short* __restrict__ Wl,
    const float* __restrict__ bias, float* __restrict__ outF,
    unsigned short* __restrict__ oh0, unsigned short* __restrict__ ol0,
    unsigned short* __restrict__ oh1, unsigned short* __restrict__ ol1,
    float scale0)
{
    __shared__ unsigned short At[2][8192];   // [buf][row*64 + swz-chunk*8]
    __shared__ unsigned short Bt[2][8192];

    const int t = threadIdx.x;
    const int lane = t & 63, wave = t >> 6;
    const int l15 = lane & 15, g = lane >> 4;
    const int wr = wave >> 1, wc = wave & 1;
    const int mb = blockIdx.x * 128;

    int which = 0, nbeff;
    if (MODE == 1) { which = blockIdx.y >> 2; nbeff = (blockIdx.y & 3) * 128; }
    else           { nbeff = blockIdx.y * 128; }
    const unsigned short* Whp = Wh + (size_t)which * 262144;
    const unsigned short* Wlp = Wl + (size_t)which * 262144;

    // staging: thread t -> row t>>1 (0..127), k-half t&1 (16 elems)
    const int srow = t >> 1, sh = t & 1;
    const size_t gAr = (size_t)(mb + srow) * 512 + sh * 16;
    const size_t gBr = (size_t)(nbeff + srow) * 512 + sh * 16;
    const int sw = srow & 7;
    const int dA0 = srow * 64 + (((sh * 2 + 0) ^ sw) * 8);   // hi chunks
    const int dA1 = srow * 64 + (((sh * 2 + 1) ^ sw) * 8);
    const int dA2 = srow * 64 + (((sh * 2 + 4) ^ sw) * 8);   // lo chunks
    const int dA3 = srow * 64 + (((sh * 2 + 5) ^ sw) * 8);

    bf16x8 sA[4], sB[4];
#define GLOAD(K0) do {                                                              \
        sA[0] = *(const bf16x8*)&Ah[gAr + (K0)];  sA[1] = *(const bf16x8*)&Ah[gAr + (K0) + 8];  \
        sA[2] = *(const bf16x8*)&Al[gAr + (K0)];  sA[3] = *(const bf16x8*)&Al[gAr + (K0) + 8];  \
        sB[0] = *(const bf16x8*)&Whp[gBr + (K0)]; sB[1] = *(const bf16x8*)&Whp[gBr + (K0) + 8]; \
        sB[2] = *(const bf16x8*)&Wlp[gBr + (K0)]; sB[3] = *(const bf16x8*)&Wlp[gBr + (K0) + 8]; \
    } while (0)
#define SWRITE(BB) do {                                                             \
        *(bf16x8*)&At[BB][dA0] = sA[0]; *(bf16x8*)&At[BB][dA1] = sA[1];             \
        *(bf16x8*)&At[BB][dA2] = sA[2]; *(bf16x8*)&At[BB][dA3] = sA[3];             \
        *(bf16x8*)&Bt[BB][dA0] = sB[0]; *(bf16x8*)&Bt[BB][dA1] = sB[1];             \
        *(bf16x8*)&Bt[BB][dA2] = sB[2]; *(bf16x8*)&Bt[BB][dA3] = sB[3];             \
    } while (0)

    f32x4 acc[4][4];
#pragma unroll
    for (int mi = 0; mi < 4; ++mi)
#pragma unroll
        for (int ni = 0; ni < 4; ++ni) acc[mi][ni] = (f32x4){0.f, 0.f, 0.f, 0.f};

    GLOAD(0); SWRITE(0); __syncthreads();
    int cur = 0;
    for (int ks = 0; ks < 16; ++ks) {
        if (ks < 15) GLOAD((ks + 1) * 32);

        bf16x8 afh[4], afl[4], wfh[4], wfl[4];
#pragma unroll
        for (int mi = 0; mi < 4; ++mi) {
            const int ar = wr * 64 + mi * 16 + l15, asw = ar & 7;
            afh[mi] = *(const bf16x8*)&At[cur][ar * 64 + ((g ^ asw) * 8)];
            afl[mi] = *(const bf16x8*)&At[cur][ar * 64 + (((g + 4) ^ asw) * 8)];
        }
#pragma unroll
        for (int ni = 0; ni < 4; ++ni) {
            const int br = wc * 64 + ni * 16 + l15, bsw = br & 7;
            wfh[ni] = *(const bf16x8*)&Bt[cur][br * 64 + ((g ^ bsw) * 8)];
            wfl[ni] = *(const bf16x8*)&Bt[cur][br * 64 + (((g + 4) ^ bsw) * 8)];
        }
#pragma unroll
        for (int mi = 0; mi < 4; ++mi)
#pragma unroll
            for (int ni = 0; ni < 4; ++ni) {
                acc[mi][ni] = __builtin_amdgcn_mfma_f32_16x16x32_bf16(afh[mi], wfh[ni], acc[mi][ni], 0, 0, 0);
                acc[mi][ni] = __builtin_amdgcn_mfma_f32_16x16x32_bf16(afl[mi], wfh[ni], acc[mi][ni], 0, 0, 0);
                acc[mi][ni] = __builtin_amdgcn_mfma_f32_16x16x32_bf16(afh[mi], wfl[ni], acc[mi][ni], 0, 0, 0);
            }

        if (ks < 15) SWRITE(cur ^ 1);
        __syncthreads();
        cur ^= 1;
    }
#undef GLOAD
#undef SWRITE

    if (MODE == 0) {
#pragma unroll
        for (int ni = 0; ni < 4; ++ni) {
            const int col = nbeff + wc * 64 + ni * 16 + l15;
            const float bv = bias[col];
#pragma unroll
            for (int mi = 0; mi < 4; ++mi) {
                const int m0 = mb + wr * 64 + mi * 16 + g * 4;
#pragma unroll
                for (int r = 0; r < 4; ++r)
                    outF[(size_t)(m0 + r) * 512 + col] = acc[mi][ni][r] + bv;
            }
        }
    } else if (MODE == 1) {
        unsigned short* oh = which ? oh1 : oh0;
        unsigned short* ol = which ? ol1 : ol0;
        const float scl = which ? 1.0f : scale0;
#pragma unroll
        for (int ni = 0; ni < 4; ++ni) {
            const int col = nbeff + wc * 64 + ni * 16 + l15;   // 0..511 within this W
            const int hh = col >> 6, dd = col & 63;
#pragma unroll
            for (int mi = 0; mi < 4; ++mi) {
                const int m0 = mb + wr * 64 + mi * 16 + g * 4;
                const int b = m0 >> 12, seq0 = m0 & (N_ - 1);
                const size_t base = ((size_t)(b * H_ + hh) * N_ + seq0) * 64 + dd;
#pragma unroll
                for (int r = 0; r < 4; ++r) {
                    const float s = acc[mi][ni][r] * scl;
                    const unsigned short hv = f2bf(s);
                    oh[base + (size_t)r * 64] = hv;
                    ol[base + (size_t)r * 64] = f2bf(s - bf2f(hv));
                }
            }
        }
    } else {  // MODE 2: v transposed [bh][64][4096]
#pragma unroll
        for (int ni = 0; ni < 4; ++ni) {
            const int col = nbeff + wc * 64 + ni * 16 + l15;
            const int hh = col >> 6, dd = col & 63;
#pragma unroll
            for (int mi = 0; mi < 4; ++mi) {
                const int m0 = mb + wr * 64 + mi * 16 + g * 4;
                const int b = m0 >> 12, seq0 = m0 & (N_ - 1);
                const size_t base = ((size_t)((b * H_ + hh) * 64) + dd) * N_ + seq0;
                const float s0 = acc[mi][ni][0], s1 = acc[mi][ni][1],
                            s2 = acc[mi][ni][2], s3 = acc[mi][ni][3];
                ushort4 hv, lv;
                hv.x = f2bf(s0); hv.y = f2bf(s1); hv.z = f2bf(s2); hv.w = f2bf(s3);
                lv.x = f2bf(s0 - bf2f(hv.x)); lv.y = f2bf(s1 - bf2f(hv.y));
                lv.z = f2bf(s2 - bf2f(hv.z)); lv.w = f2bf(s3 - bf2f(hv.w));
                *(ushort4*)&oh0[base] = hv;
                *(ushort4*)&ol0[base] = lv;
            }
        }
    }
}

// ---------------------------------------------------------------------------
// Flash attention (unchanged structure from the PASSING round-4 kernel).
// Only the epilogue differs: att is emitted as split bf16 hi/lo so the final
// projection can run on MFMA too.
// ---------------------------------------------------------------------------
__global__ __launch_bounds__(256, 2) void attn_mfma(
    const unsigned short* __restrict__ qh, const unsigned short* __restrict__ ql,
    const unsigned short* __restrict__ kh, const unsigned short* __restrict__ kl,
    const unsigned short* __restrict__ vth, const unsigned short* __restrict__ vtl,
    unsigned short* __restrict__ oh, unsigned short* __restrict__ ol)
{
    __shared__ unsigned short Kb[2][2][4096];   // [buf][hi/lo][lds_row*64 + swz col]
    __shared__ unsigned short Vb[2][2][4096];   // rows = d (V transposed), linear

    const int t    = threadIdx.x;
    const int lane = t & 63;
    const int wave = t >> 6;
    const int l15  = lane & 15;
    const int g    = lane >> 4;
    const int bh   = blockIdx.y;
    const int qbase = blockIdx.x * 128 + wave * 32;

    bf16x8 qf[2][2][2];   // [rowtile][chunk][hi/lo]
#pragma unroll
    for (int rt = 0; rt < 2; ++rt)
#pragma unroll
        for (int c = 0; c < 2; ++c) {
            const size_t src = ((size_t)bh * N_ + qbase + rt * 16 + l15) * 64 + c * 32 + g * 8;
            qf[rt][c][0] = *(const bf16x8*)&qh[src];
            qf[rt][c][1] = *(const bf16x8*)&ql[src];
        }

    f32x4 O[2][4];
#pragma unroll
    for (int rt = 0; rt < 2; ++rt)
#pragma unroll
        for (int dt = 0; dt < 4; ++dt) O[rt][dt] = (f32x4){0.f, 0.f, 0.f, 0.f};
    float mreg[2] = {-3.0e38f, -3.0e38f};
    float lreg[2] = {0.f, 0.f};

    const int srow = t >> 3;          // 0..31
    const int sc16 = t & 7;
    const size_t kbase = (size_t)bh * N_ * 64;
    const size_t vbase = (size_t)bh * 64 * N_;
    const int vdst0 = srow * 64 + ((sc16 ^ (srow & 7)) * 8);
    const int vdst1 = (srow + 32) * 64 + ((sc16 ^ ((srow + 32) & 7)) * 8);
    const int krho  = (((srow >> 2) & 1) << 4) | (((srow >> 3) & 3) << 2) | (srow & 3);
    const int kdst0 = krho * 64 + ((sc16 ^ (krho & 7)) * 8);
    const int kdst1 = kdst0 + 32 * 64;

    bf16x8 sKh[2], sKl[2], sVh[2], sVl[2];

#define LOADT(KT) do {                                                          \
        const size_t gK0 = kbase + ((size_t)((KT) * 64 + srow)) * 64 + sc16 * 8;      \
        const size_t gK1 = kbase + ((size_t)((KT) * 64 + srow + 32)) * 64 + sc16 * 8; \
        const size_t gV0 = vbase + (size_t)srow * N_ + (KT) * 64 + sc16 * 8;          \
        const size_t gV1 = vbase + (size_t)(srow + 32) * N_ + (KT) * 64 + sc16 * 8;   \
        sKh[0] = *(const bf16x8*)&kh[gK0];  sKh[1] = *(const bf16x8*)&kh[gK1];  \
        sKl[0] = *(const bf16x8*)&kl[gK0];  sKl[1] = *(const bf16x8*)&kl[gK1];  \
        sVh[0] = *(const bf16x8*)&vth[gV0]; sVh[1] = *(const bf16x8*)&vth[gV1]; \
        sVl[0] = *(const bf16x8*)&vtl[gV0]; sVl[1] = *(const bf16x8*)&vtl[gV1]; \
    } while (0)

#define WRITET(BB) do {                                                         \
        *(bf16x8*)&Kb[BB][0][kdst0] = sKh[0]; *(bf16x8*)&Kb[BB][0][kdst1] = sKh[1]; \
        *(bf16x8*)&Kb[BB][1][kdst0] = sKl[0]; *(bf16x8*)&Kb[BB][1][kdst1] = sKl[1]; \
        *(bf16x8*)&Vb[BB][0][vdst0] = sVh[0]; *(bf16x8*)&Vb[BB][0][vdst1] = sVh[1]; \
        *(bf16x8*)&Vb[BB][1][vdst0] = sVl[0]; *(bf16x8*)&Vb[BB][1][vdst1] = sVl[1]; \
    } while (0)

    LOADT(0);
    WRITET(0);
    __syncthreads();

    int cur = 0;
    for (int kt = 0; kt < N_ / 64; ++kt) {
        const bool pf = (kt + 1 < N_ / 64);
        if (pf) LOADT(kt + 1);

        f32x4 S[2][4];
#pragma unroll
        for (int rt = 0; rt < 2; ++rt)
#pragma unroll
            for (int j = 0; j < 4; ++j) S[rt][j] = (f32x4){0.f, 0.f, 0.f, 0.f};

#pragma unroll
        for (int j = 0; j < 4; ++j) {
            const int krow = j * 16 + l15;
            const int rb = krow * 64, sw2 = (krow & 7) * 8;
#pragma unroll
            for (int c = 0; c < 2; ++c) {
                const int off = rb + (((c * 4 + g) * 8) ^ sw2);
                bf16x8 kfh = *(const bf16x8*)&Kb[cur][0][off];
                bf16x8 kfl = *(const bf16x8*)&Kb[cur][1][off];
#pragma unroll
                for (int rt = 0; rt < 2; ++rt) {
                    S[rt][j] = __builtin_amdgcn_mfma_f32_16x16x32_bf16(kfh, qf[rt][c][0], S[rt][j], 0, 0, 0);
                    S[rt][j] = __builtin_amdgcn_mfma_f32_16x16x32_bf16(kfl, qf[rt][c][0], S[rt][j], 0, 0, 0);
                    S[rt][j] = __builtin_amdgcn_mfma_f32_16x16x32_bf16(kfh, qf[rt][c][1], S[rt][j], 0, 0, 0);
                }
            }
        }

        bf16x8 pah[2][2], pal[2][2];
#pragma unroll
        for (int rt = 0; rt < 2; ++rt) {
            float pmax = -3.0e38f;
#pragma unroll
            for (int j = 0; j < 4; ++j)
#pragma unroll
                for (int r = 0; r < 4; ++r) pmax = fmaxf(pmax, S[rt][j][r]);
            pmax = fmaxf(pmax, __shfl_xor(pmax, 16));
            pmax = fmaxf(pmax, __shfl_xor(pmax, 32));

            const float mold = mreg[rt];
            if (!__all(pmax <= mold + 8.0f)) {       // T13 defer-max
                const float mnew = fmaxf(mold, pmax);
                const float alpha = exp2f(mold - mnew);
#pragma unroll
                for (int dt = 0; dt < 4; ++dt)
#pragma unroll
                    for (int r = 0; r < 4; ++r) O[rt][dt][r] *= alpha;
                lreg[rt] *= alpha;
                mreg[rt] = mnew;
            }
            const float mb2 = mreg[rt];

            float lsum = 0.f;
#pragma unroll
            for (int j = 0; j < 4; ++j)
#pragma unroll
                for (int r = 0; r < 4; ++r) {
                    S[rt][j][r] = exp2f(S[rt][j][r] - mb2);
                    lsum += S[rt][j][r];
                }
            lreg[rt] += lsum;

#pragma unroll
            for (int c = 0; c < 2; ++c) {
                const f32x4 s0 = S[rt][2 * c], s1 = S[rt][2 * c + 1];
                union { unsigned int u[4]; bf16x8 v; } th, tl;
                th.u[0] = cvt_pk_bf16(s0[0], s0[1]);
                th.u[1] = cvt_pk_bf16(s0[2], s0[3]);
                th.u[2] = cvt_pk_bf16(s1[0], s1[1]);
                th.u[3] = cvt_pk_bf16(s1[2], s1[3]);
                tl.u[0] = cvt_pk_bf16(s0[0] - lo_bf(th.u[0]), s0[1] - hi_bf(th.u[0]));
                tl.u[1] = cvt_pk_bf16(s0[2] - lo_bf(th.u[1]), s0[3] - hi_bf(th.u[1]));
                tl.u[2] = cvt_pk_bf16(s1[0] - lo_bf(th.u[2]), s1[1] - hi_bf(th.u[2]));
                tl.u[3] = cvt_pk_bf16(s1[2] - lo_bf(th.u[3]), s1[3] - hi_bf(th.u[3]));
                pah[rt][c] = th.v;
                pal[rt][c] = tl.v;
            }
        }

#pragma unroll
        for (int c = 0; c < 2; ++c) {
#pragma unroll
            for (int dt = 0; dt < 4; ++dt) {
                const int vrow = dt * 16 + l15;
                const int off = vrow * 64 + (((c * 4 + g) * 8) ^ ((vrow & 7) * 8));
                bf16x8 vfh = *(const bf16x8*)&Vb[cur][0][off];
                bf16x8 vfl = *(const bf16x8*)&Vb[cur][1][off];
#pragma unroll
                for (int rt = 0; rt < 2; ++rt) {
                    O[rt][dt] = __builtin_amdgcn_mfma_f32_16x16x32_bf16(vfh, pah[rt][c], O[rt][dt], 0, 0, 0);
                    O[rt][dt] = __builtin_amdgcn_mfma_f32_16x16x32_bf16(vfl, pah[rt][c], O[rt][dt], 0, 0, 0);
                    O[rt][dt] = __builtin_amdgcn_mfma_f32_16x16x32_bf16(vfh, pal[rt][c], O[rt][dt], 0, 0, 0);
                }
            }
        }

        if (pf) WRITET(cur ^ 1);
        __syncthreads();
        cur ^= 1;
    }

    // ---- epilogue: normalize, split to bf16 hi/lo, write [b n][h*64+d] ----
    const int b = bh >> 3, hh = bh & 7;
#pragma unroll
    for (int rt = 0; rt < 2; ++rt) {
        float lt = lreg[rt];
        lt += __shfl_xor(lt, 16);
        lt += __shfl_xor(lt, 32);
        const float inv = 1.0f / lt;
        const int n = qbase + rt * 16 + l15;
        const size_t rowbase = ((size_t)(b * N_) + n) * 512 + hh * 64 + g * 4;
#pragma unroll
        for (int dt = 0; dt < 4; ++dt) {
            const float s0 = O[rt][dt][0] * inv, s1 = O[rt][dt][1] * inv,
                        s2 = O[rt][dt][2] * inv, s3 = O[rt][dt][3] * inv;
            ushort4 hv, lv;
            hv.x = f2bf(s0); hv.y = f2bf(s1); hv.z = f2bf(s2); hv.w = f2bf(s3);
            lv.x = f2bf(s0 - bf2f(hv.x)); lv.y = f2bf(s1 - bf2f(hv.y));
            lv.z = f2bf(s2 - bf2f(hv.z)); lv.w = f2bf(s3 - bf2f(hv.w));
            *(ushort4*)&oh[rowbase + dt * 16] = hv;
            *(ushort4*)&ol[rowbase + dt * 16] = lv;
        }
    }
#undef LOADT
#undef WRITET
}

// ---------------------------------------------------------------------------
extern "C" void kernel_launch(void* const* d_in, const int* in_sizes, int n_in,
                              void* d_out, int out_size, void* d_ws, size_t ws_size,
                              hipStream_t stream)
{
    const float* x  = (const float*)d_in[0];
    const float* Wq = (const float*)d_in[1];
    const float* Wk = (const float*)d_in[2];
    const float* Wv = (const float*)d_in[3];
    const float* Wo = (const float*)d_in[4];
    const float* bo = (const float*)d_in[5];

    unsigned char* w8 = (unsigned char*)d_ws;
    const size_t MB = 1024 * 1024;
    unsigned short* xh  = (unsigned short*)(w8);            // 8 MB
    unsigned short* xl  = (unsigned short*)(w8 + 8  * MB);  // 8 MB
    unsigned short* wh  = (unsigned short*)(w8 + 16 * MB);  // 2 MB [4][512][512]
    unsigned short* wl  = (unsigned short*)(w8 + 18 * MB);  // 2 MB
    unsigned short* qh  = (unsigned short*)(w8 + 20 * MB);
    unsigned short* ql  = (unsigned short*)(w8 + 28 * MB);
    unsigned short* kh  = (unsigned short*)(w8 + 36 * MB);
    unsigned short* kl  = (unsigned short*)(w8 + 44 * MB);
    unsigned short* vth = (unsigned short*)(w8 + 52 * MB);
    unsigned short* vtl = (unsigned short*)(w8 + 60 * MB);  // end 68 MB
    // att (split) aliases xh/xl: x is dead once the QKV GEMMs complete.
    unsigned short* ah = xh;
    unsigned short* al = xl;
    float* out = (float*)d_out;

    conv_split<<<1024, 256, 0, stream>>>(x, xh, xl, M_ * 512 / 4);
    conv_w4<<<dim3(256, 4), 256, 0, stream>>>(Wq, Wk, Wv, Wo, wh, wl);

    // q/k fused: grid y 0-3 -> Wq (scaled), 4-7 -> Wk
    gemm_mfma<1><<<dim3(64, 8), 256, 0, stream>>>(xh, xl, wh, wl, nullptr, nullptr,
                                                  qh, ql, kh, kl, QSCALE_);
    // v transposed
    gemm_mfma<2><<<dim3(64, 4), 256, 0, stream>>>(xh, xl, wh + 2 * 262144, wl + 2 * 262144,
                                                  nullptr, nullptr, vth, vtl, nullptr, nullptr, 1.0f);

    attn_mfma<<<dim3(N_ / 128, 16), 256, 0, stream>>>(qh, ql, kh, kl, vth, vtl, ah, al);

    // final projection + bias
    gemm_mfma<0><<<dim3(64, 4), 256, 0, stream>>>(ah, al, wh + 3 * 262144, wl + 3 * 262144,
                                                  bo, out, nullptr, nullptr, nullptr, nullptr, 1.0f);
}

// Round 7
// 323.550 us; speedup vs baseline: 12.5695x; 1.1303x over previous
//
#include <hip/hip_runtime.h>
#include <hip/hip_bf16.h>

#define B_ 2
#define N_ 4096
#define D_ 512
#define H_ 8
#define M_ (B_*N_)              // 8192 rows
#define QSCALE_ 0.18033688011f  // 0.125 * log2(e): softmax runs in log2 domain

typedef short bf16x8 __attribute__((ext_vector_type(8)));
typedef float f32x4  __attribute__((ext_vector_type(4)));

static __device__ __forceinline__ unsigned short f2bf(float f) {
    union { float f; unsigned int u; } v; v.f = f;
    unsigned int r = v.u + 0x7fffu + ((v.u >> 16) & 1u);   // RNE
    return (unsigned short)(r >> 16);
}
static __device__ __forceinline__ float bf2f(unsigned short h) {
    union { unsigned int u; float f; } v; v.u = ((unsigned int)h) << 16;
    return v.f;
}
static __device__ __forceinline__ unsigned int cvt_pk_bf16(float a, float b) {
    unsigned int r;  // D[15:0]=bf16(a), D[31:16]=bf16(b)
    asm("v_cvt_pk_bf16_f32 %0, %1, %2" : "=v"(r) : "v"(a), "v"(b));
    return r;
}

// ---------------------------------------------------------------------------
// fp32 -> split bf16 hi/lo, grid-stride, float4/ushort4 vectorized.
// ---------------------------------------------------------------------------
__global__ void conv_split(const float* __restrict__ src, unsigned short* __restrict__ dh,
                           unsigned short* __restrict__ dl, int n4)
{
    int i = blockIdx.x * blockDim.x + threadIdx.x;
    const int stride = gridDim.x * blockDim.x;
    for (; i < n4; i += stride) {
        float4 v = ((const float4*)src)[i];
        ushort4 hv, lv;
        hv.x = f2bf(v.x); hv.y = f2bf(v.y); hv.z = f2bf(v.z); hv.w = f2bf(v.w);
        lv.x = f2bf(v.x - bf2f(hv.x)); lv.y = f2bf(v.y - bf2f(hv.y));
        lv.z = f2bf(v.z - bf2f(hv.z)); lv.w = f2bf(v.w - bf2f(hv.w));
        ((ushort4*)dh)[i] = hv;
        ((ushort4*)dl)[i] = lv;
    }
}

// 4 weight matrices (512x512 each) -> wbuf hi/lo [4][512][512]
__global__ void conv_w4(const float* __restrict__ w0, const float* __restrict__ w1,
                        const float* __restrict__ w2, const float* __restrict__ w3,
                        unsigned short* __restrict__ dh, unsigned short* __restrict__ dl)
{
    const int which = blockIdx.y;
    const float* src = which == 0 ? w0 : which == 1 ? w1 : which == 2 ? w2 : w3;
    const int i = blockIdx.x * 256 + threadIdx.x;          // 0..65535 float4s
    float4 v = ((const float4*)src)[i];
    ushort4 hv, lv;
    hv.x = f2bf(v.x); hv.y = f2bf(v.y); hv.z = f2bf(v.z); hv.w = f2bf(v.w);
    lv.x = f2bf(v.x - bf2f(hv.x)); lv.y = f2bf(v.y - bf2f(hv.y));
    lv.z = f2bf(v.z - bf2f(hv.z)); lv.w = f2bf(v.w - bf2f(hv.w));
    ((ushort4*)(dh + (size_t)which * 262144))[i] = hv;
    ((ushort4*)(dl + (size_t)which * 262144))[i] = lv;
}

// ---------------------------------------------------------------------------
// Split-bf16 MFMA GEMM: Y = A @ W^T, A[M][512] hi/lo bf16, W[512][512] hi/lo.
// 3-term: Ah*Wh + Al*Wh + Ah*Wl. Tile 128x128, BK=32, 4 waves (2x2), each
// wave 64x64 = 4x4 MFMA frags. mfma(af,wf) -> D[m = g*4+r][n = l15].
// MODE 0: fp32 out[m][512] + bias                       (final projection)
// MODE 1: fused QKV. blockIdx.y: 0-3 -> q (scaled, split [bh][n][64]),
//         4-7 -> k (split [bh][n][64]), 8-11 -> v (split transposed [bh][64][4096])
// ---------------------------------------------------------------------------
template<int MODE>
__global__ __launch_bounds__(256, 2) void gemm_mfma(
    const unsigned short* __restrict__ Ah, const unsigned short* __restrict__ Al,
    const unsigned short* __restrict__ Wh, const unsigned short* __restrict__ Wl,
    const float* __restrict__ bias, float* __restrict__ outF,
    unsigned short* __restrict__ oh0, unsigned short* __restrict__ ol0,
    unsigned short* __restrict__ oh1, unsigned short* __restrict__ ol1,
    unsigned short* __restrict__ oh2, unsigned short* __restrict__ ol2,
    float scale0)
{
    __shared__ unsigned short At[2][8192];   // [buf][row*64 + swz-chunk*8]
    __shared__ unsigned short Bt[2][8192];

    const int t = threadIdx.x;
    const int lane = t & 63, wave = t >> 6;
    const int l15 = lane & 15, g = lane >> 4;
    const int wr = wave >> 1, wc = wave & 1;
    const int mb = blockIdx.x * 128;

    int which = 0, nbeff;
    if (MODE == 1) { which = blockIdx.y >> 2; nbeff = (blockIdx.y & 3) * 128; }
    else           { nbeff = blockIdx.y * 128; }
    const unsigned short* Whp = Wh + (size_t)which * 262144;
    const unsigned short* Wlp = Wl + (size_t)which * 262144;

    // staging: thread t -> row t>>1 (0..127), k-half t&1 (16 elems)
    const int srow = t >> 1, sh = t & 1;
    const size_t gAr = (size_t)(mb + srow) * 512 + sh * 16;
    const size_t gBr = (size_t)(nbeff + srow) * 512 + sh * 16;
    const int sw = srow & 7;
    const int dA0 = srow * 64 + (((sh * 2 + 0) ^ sw) * 8);   // hi chunks
    const int dA1 = srow * 64 + (((sh * 2 + 1) ^ sw) * 8);
    const int dA2 = srow * 64 + (((sh * 2 + 4) ^ sw) * 8);   // lo chunks
    const int dA3 = srow * 64 + (((sh * 2 + 5) ^ sw) * 8);

    bf16x8 sA[4], sB[4];
#define GLOAD(K0) do {                                                              \
        sA[0] = *(const bf16x8*)&Ah[gAr + (K0)];  sA[1] = *(const bf16x8*)&Ah[gAr + (K0) + 8];  \
        sA[2] = *(const bf16x8*)&Al[gAr + (K0)];  sA[3] = *(const bf16x8*)&Al[gAr + (K0) + 8];  \
        sB[0] = *(const bf16x8*)&Whp[gBr + (K0)]; sB[1] = *(const bf16x8*)&Whp[gBr + (K0) + 8]; \
        sB[2] = *(const bf16x8*)&Wlp[gBr + (K0)]; sB[3] = *(const bf16x8*)&Wlp[gBr + (K0) + 8]; \
    } while (0)
#define SWRITE(BB) do {                                                             \
        *(bf16x8*)&At[BB][dA0] = sA[0]; *(bf16x8*)&At[BB][dA1] = sA[1];             \
        *(bf16x8*)&At[BB][dA2] = sA[2]; *(bf16x8*)&At[BB][dA3] = sA[3];             \
        *(bf16x8*)&Bt[BB][dA0] = sB[0]; *(bf16x8*)&Bt[BB][dA1] = sB[1];             \
        *(bf16x8*)&Bt[BB][dA2] = sB[2]; *(bf16x8*)&Bt[BB][dA3] = sB[3];             \
    } while (0)

    f32x4 acc[4][4];
#pragma unroll
    for (int mi = 0; mi < 4; ++mi)
#pragma unroll
        for (int ni = 0; ni < 4; ++ni) acc[mi][ni] = (f32x4){0.f, 0.f, 0.f, 0.f};

    GLOAD(0); SWRITE(0); __syncthreads();
    int cur = 0;
    for (int ks = 0; ks < 16; ++ks) {
        if (ks < 15) GLOAD((ks + 1) * 32);

        bf16x8 afh[4], afl[4], wfh[4], wfl[4];
#pragma unroll
        for (int mi = 0; mi < 4; ++mi) {
            const int ar = wr * 64 + mi * 16 + l15, asw = ar & 7;
            afh[mi] = *(const bf16x8*)&At[cur][ar * 64 + ((g ^ asw) * 8)];
            afl[mi] = *(const bf16x8*)&At[cur][ar * 64 + (((g + 4) ^ asw) * 8)];
        }
#pragma unroll
        for (int ni = 0; ni < 4; ++ni) {
            const int br = wc * 64 + ni * 16 + l15, bsw = br & 7;
            wfh[ni] = *(const bf16x8*)&Bt[cur][br * 64 + ((g ^ bsw) * 8)];
            wfl[ni] = *(const bf16x8*)&Bt[cur][br * 64 + (((g + 4) ^ bsw) * 8)];
        }
#pragma unroll
        for (int mi = 0; mi < 4; ++mi)
#pragma unroll
            for (int ni = 0; ni < 4; ++ni) {
                acc[mi][ni] = __builtin_amdgcn_mfma_f32_16x16x32_bf16(afh[mi], wfh[ni], acc[mi][ni], 0, 0, 0);
                acc[mi][ni] = __builtin_amdgcn_mfma_f32_16x16x32_bf16(afl[mi], wfh[ni], acc[mi][ni], 0, 0, 0);
                acc[mi][ni] = __builtin_amdgcn_mfma_f32_16x16x32_bf16(afh[mi], wfl[ni], acc[mi][ni], 0, 0, 0);
            }

        if (ks < 15) SWRITE(cur ^ 1);
        __syncthreads();
        cur ^= 1;
    }
#undef GLOAD
#undef SWRITE

    if (MODE == 0) {
#pragma unroll
        for (int ni = 0; ni < 4; ++ni) {
            const int col = nbeff + wc * 64 + ni * 16 + l15;
            const float bv = bias[col];
#pragma unroll
            for (int mi = 0; mi < 4; ++mi) {
                const int m0 = mb + wr * 64 + mi * 16 + g * 4;
#pragma unroll
                for (int r = 0; r < 4; ++r)
                    outF[(size_t)(m0 + r) * 512 + col] = acc[mi][ni][r] + bv;
            }
        }
    } else if (which < 2) {   // q or k: split [bh][seq][64]
        unsigned short* oh = which ? oh1 : oh0;
        unsigned short* ol = which ? ol1 : ol0;
        const float scl = which ? 1.0f : scale0;
#pragma unroll
        for (int ni = 0; ni < 4; ++ni) {
            const int col = nbeff + wc * 64 + ni * 16 + l15;   // 0..511 within this W
            const int hh = col >> 6, dd = col & 63;
#pragma unroll
            for (int mi = 0; mi < 4; ++mi) {
                const int m0 = mb + wr * 64 + mi * 16 + g * 4;
                const int b = m0 >> 12, seq0 = m0 & (N_ - 1);
                const size_t base = ((size_t)(b * H_ + hh) * N_ + seq0) * 64 + dd;
#pragma unroll
                for (int r = 0; r < 4; ++r) {
                    const float s = acc[mi][ni][r] * scl;
                    const unsigned short hv = f2bf(s);
                    oh[base + (size_t)r * 64] = hv;
                    ol[base + (size_t)r * 64] = f2bf(s - bf2f(hv));
                }
            }
        }
    } else {  // v: split transposed [bh][64][4096]
#pragma unroll
        for (int ni = 0; ni < 4; ++ni) {
            const int col = nbeff + wc * 64 + ni * 16 + l15;
            const int hh = col >> 6, dd = col & 63;
#pragma unroll
            for (int mi = 0; mi < 4; ++mi) {
                const int m0 = mb + wr * 64 + mi * 16 + g * 4;
                const int b = m0 >> 12, seq0 = m0 & (N_ - 1);
                const size_t base = ((size_t)((b * H_ + hh) * 64) + dd) * N_ + seq0;
                const float s0 = acc[mi][ni][0], s1 = acc[mi][ni][1],
                            s2 = acc[mi][ni][2], s3 = acc[mi][ni][3];
                ushort4 hv, lv;
                hv.x = f2bf(s0); hv.y = f2bf(s1); hv.z = f2bf(s2); hv.w = f2bf(s3);
                lv.x = f2bf(s0 - bf2f(hv.x)); lv.y = f2bf(s1 - bf2f(hv.y));
                lv.z = f2bf(s2 - bf2f(hv.z)); lv.w = f2bf(s3 - bf2f(hv.w));
                *(ushort4*)&oh2[base] = hv;
                *(ushort4*)&ol2[base] = lv;
            }
        }
    }
}

// ---------------------------------------------------------------------------
// Flash attention. Structure = the PASSING round-4/5 kernel. Changes:
//  * PV is now 2-term (Vh*Ph + Vl*Ph): the P-residual term Vh*Pl and its
//    whole pack are dropped (error ~ weighted avg of |Pl|<=2^-9*P residuals,
//    well under threshold). QK^T stays 3-term (score errors exponentiate).
//  * T5: s_setprio(1) around both MFMA clusters.
// ---------------------------------------------------------------------------
__global__ __launch_bounds__(256, 2) void attn_mfma(
    const unsigned short* __restrict__ qh, const unsigned short* __restrict__ ql,
    const unsigned short* __restrict__ kh, const unsigned short* __restrict__ kl,
    const unsigned short* __restrict__ vth, const unsigned short* __restrict__ vtl,
    unsigned short* __restrict__ oh, unsigned short* __restrict__ ol)
{
    __shared__ unsigned short Kb[2][2][4096];   // [buf][hi/lo][lds_row*64 + swz col]
    __shared__ unsigned short Vb[2][2][4096];   // rows = d (V transposed), linear

    const int t    = threadIdx.x;
    const int lane = t & 63;
    const int wave = t >> 6;
    const int l15  = lane & 15;
    const int g    = lane >> 4;
    const int bh   = blockIdx.y;
    const int qbase = blockIdx.x * 128 + wave * 32;

    bf16x8 qf[2][2][2];   // [rowtile][chunk][hi/lo]
#pragma unroll
    for (int rt = 0; rt < 2; ++rt)
#pragma unroll
        for (int c = 0; c < 2; ++c) {
            const size_t src = ((size_t)bh * N_ + qbase + rt * 16 + l15) * 64 + c * 32 + g * 8;
            qf[rt][c][0] = *(const bf16x8*)&qh[src];
            qf[rt][c][1] = *(const bf16x8*)&ql[src];
        }

    f32x4 O[2][4];
#pragma unroll
    for (int rt = 0; rt < 2; ++rt)
#pragma unroll
        for (int dt = 0; dt < 4; ++dt) O[rt][dt] = (f32x4){0.f, 0.f, 0.f, 0.f};
    float mreg[2] = {-3.0e38f, -3.0e38f};
    float lreg[2] = {0.f, 0.f};

    const int srow = t >> 3;          // 0..31
    const int sc16 = t & 7;
    const size_t kbase = (size_t)bh * N_ * 64;
    const size_t vbase = (size_t)bh * 64 * N_;
    const int vdst0 = srow * 64 + ((sc16 ^ (srow & 7)) * 8);
    const int vdst1 = (srow + 32) * 64 + ((sc16 ^ ((srow + 32) & 7)) * 8);
    const int krho  = (((srow >> 2) & 1) << 4) | (((srow >> 3) & 3) << 2) | (srow & 3);
    const int kdst0 = krho * 64 + ((sc16 ^ (krho & 7)) * 8);
    const int kdst1 = kdst0 + 32 * 64;

    bf16x8 sKh[2], sKl[2], sVh[2], sVl[2];

#define LOADT(KT) do {                                                          \
        const size_t gK0 = kbase + ((size_t)((KT) * 64 + srow)) * 64 + sc16 * 8;      \
        const size_t gK1 = kbase + ((size_t)((KT) * 64 + srow + 32)) * 64 + sc16 * 8; \
        const size_t gV0 = vbase + (size_t)srow * N_ + (KT) * 64 + sc16 * 8;          \
        const size_t gV1 = vbase + (size_t)(srow + 32) * N_ + (KT) * 64 + sc16 * 8;   \
        sKh[0] = *(const bf16x8*)&kh[gK0];  sKh[1] = *(const bf16x8*)&kh[gK1];  \
        sKl[0] = *(const bf16x8*)&kl[gK0];  sKl[1] = *(const bf16x8*)&kl[gK1];  \
        sVh[0] = *(const bf16x8*)&vth[gV0]; sVh[1] = *(const bf16x8*)&vth[gV1]; \
        sVl[0] = *(const bf16x8*)&vtl[gV0]; sVl[1] = *(const bf16x8*)&vtl[gV1]; \
    } while (0)

#define WRITET(BB) do {                                                         \
        *(bf16x8*)&Kb[BB][0][kdst0] = sKh[0]; *(bf16x8*)&Kb[BB][0][kdst1] = sKh[1]; \
        *(bf16x8*)&Kb[BB][1][kdst0] = sKl[0]; *(bf16x8*)&Kb[BB][1][kdst1] = sKl[1]; \
        *(bf16x8*)&Vb[BB][0][vdst0] = sVh[0]; *(bf16x8*)&Vb[BB][0][vdst1] = sVh[1]; \
        *(bf16x8*)&Vb[BB][1][vdst0] = sVl[0]; *(bf16x8*)&Vb[BB][1][vdst1] = sVl[1]; \
    } while (0)

    LOADT(0);
    WRITET(0);
    __syncthreads();

    int cur = 0;
    for (int kt = 0; kt < N_ / 64; ++kt) {
        const bool pf = (kt + 1 < N_ / 64);
        if (pf) LOADT(kt + 1);

        f32x4 S[2][4];
#pragma unroll
        for (int rt = 0; rt < 2; ++rt)
#pragma unroll
            for (int j = 0; j < 4; ++j) S[rt][j] = (f32x4){0.f, 0.f, 0.f, 0.f};

        __builtin_amdgcn_s_setprio(1);
#pragma unroll
        for (int j = 0; j < 4; ++j) {
            const int krow = j * 16 + l15;
            const int rb = krow * 64, sw2 = (krow & 7) * 8;
#pragma unroll
            for (int c = 0; c < 2; ++c) {
                const int off = rb + (((c * 4 + g) * 8) ^ sw2);
                bf16x8 kfh = *(const bf16x8*)&Kb[cur][0][off];
                bf16x8 kfl = *(const bf16x8*)&Kb[cur][1][off];
#pragma unroll
                for (int rt = 0; rt < 2; ++rt) {
                    S[rt][j] = __builtin_amdgcn_mfma_f32_16x16x32_bf16(kfh, qf[rt][c][0], S[rt][j], 0, 0, 0);
                    S[rt][j] = __builtin_amdgcn_mfma_f32_16x16x32_bf16(kfl, qf[rt][c][0], S[rt][j], 0, 0, 0);
                    S[rt][j] = __builtin_amdgcn_mfma_f32_16x16x32_bf16(kfh, qf[rt][c][1], S[rt][j], 0, 0, 0);
                }
            }
        }
        __builtin_amdgcn_s_setprio(0);

        bf16x8 pah[2][2];
#pragma unroll
        for (int rt = 0; rt < 2; ++rt) {
            float pmax = -3.0e38f;
#pragma unroll
            for (int j = 0; j < 4; ++j)
#pragma unroll
                for (int r = 0; r < 4; ++r) pmax = fmaxf(pmax, S[rt][j][r]);
            pmax = fmaxf(pmax, __shfl_xor(pmax, 16));
            pmax = fmaxf(pmax, __shfl_xor(pmax, 32));

            const float mold = mreg[rt];
            if (!__all(pmax <= mold + 8.0f)) {       // T13 defer-max
                const float mnew = fmaxf(mold, pmax);
                const float alpha = exp2f(mold - mnew);
#pragma unroll
                for (int dt = 0; dt < 4; ++dt)
#pragma unroll
                    for (int r = 0; r < 4; ++r) O[rt][dt][r] *= alpha;
                lreg[rt] *= alpha;
                mreg[rt] = mnew;
            }
            const float mb2 = mreg[rt];

            float lsum = 0.f;
#pragma unroll
            for (int j = 0; j < 4; ++j)
#pragma unroll
                for (int r = 0; r < 4; ++r) {
                    S[rt][j][r] = exp2f(S[rt][j][r] - mb2);
                    lsum += S[rt][j][r];
                }
            lreg[rt] += lsum;

#pragma unroll
            for (int c = 0; c < 2; ++c) {
                const f32x4 s0 = S[rt][2 * c], s1 = S[rt][2 * c + 1];
                union { unsigned int u[4]; bf16x8 v; } th;
                th.u[0] = cvt_pk_bf16(s0[0], s0[1]);
                th.u[1] = cvt_pk_bf16(s0[2], s0[3]);
                th.u[2] = cvt_pk_bf16(s1[0], s1[1]);
                th.u[3] = cvt_pk_bf16(s1[2], s1[3]);
                pah[rt][c] = th.v;
            }
        }

        __builtin_amdgcn_s_setprio(1);
#pragma unroll
        for (int c = 0; c < 2; ++c) {
#pragma unroll
            for (int dt = 0; dt < 4; ++dt) {
                const int vrow = dt * 16 + l15;
                const int off = vrow * 64 + (((c * 4 + g) * 8) ^ ((vrow & 7) * 8));
                bf16x8 vfh = *(const bf16x8*)&Vb[cur][0][off];
                bf16x8 vfl = *(const bf16x8*)&Vb[cur][1][off];
#pragma unroll
                for (int rt = 0; rt < 2; ++rt) {
                    O[rt][dt] = __builtin_amdgcn_mfma_f32_16x16x32_bf16(vfh, pah[rt][c], O[rt][dt], 0, 0, 0);
                    O[rt][dt] = __builtin_amdgcn_mfma_f32_16x16x32_bf16(vfl, pah[rt][c], O[rt][dt], 0, 0, 0);
                }
            }
        }
        __builtin_amdgcn_s_setprio(0);

        if (pf) WRITET(cur ^ 1);
        __syncthreads();
        cur ^= 1;
    }

    // ---- epilogue: normalize, split to bf16 hi/lo, write [b n][h*64+d] ----
    const int b = bh >> 3, hh = bh & 7;
#pragma unroll
    for (int rt = 0; rt < 2; ++rt) {
        float lt = lreg[rt];
        lt += __shfl_xor(lt, 16);
        lt += __shfl_xor(lt, 32);
        const float inv = 1.0f / lt;
        const int n = qbase + rt * 16 + l15;
        const size_t rowbase = ((size_t)(b * N_) + n) * 512 + hh * 64 + g * 4;
#pragma unroll
        for (int dt = 0; dt < 4; ++dt) {
            const float s0 = O[rt][dt][0] * inv, s1 = O[rt][dt][1] * inv,
                        s2 = O[rt][dt][2] * inv, s3 = O[rt][dt][3] * inv;
            ushort4 hv, lv;
            hv.x = f2bf(s0); hv.y = f2bf(s1); hv.z = f2bf(s2); hv.w = f2bf(s3);
            lv.x = f2bf(s0 - bf2f(hv.x)); lv.y = f2bf(s1 - bf2f(hv.y));
            lv.z = f2bf(s2 - bf2f(hv.z)); lv.w = f2bf(s3 - bf2f(hv.w));
            *(ushort4*)&oh[rowbase + dt * 16] = hv;
            *(ushort4*)&ol[rowbase + dt * 16] = lv;
        }
    }
#undef LOADT
#undef WRITET
}

// ---------------------------------------------------------------------------
extern "C" void kernel_launch(void* const* d_in, const int* in_sizes, int n_in,
                              void* d_out, int out_size, void* d_ws, size_t ws_size,
                              hipStream_t stream)
{
    const float* x  = (const float*)d_in[0];
    const float* Wq = (const float*)d_in[1];
    const float* Wk = (const float*)d_in[2];
    const float* Wv = (const float*)d_in[3];
    const float* Wo = (const float*)d_in[4];
    const float* bo = (const float*)d_in[5];

    unsigned char* w8 = (unsigned char*)d_ws;
    const size_t MB = 1024 * 1024;
    unsigned short* xh  = (unsigned short*)(w8);            // 8 MB
    unsigned short* xl  = (unsigned short*)(w8 + 8  * MB);  // 8 MB
    unsigned short* wh  = (unsigned short*)(w8 + 16 * MB);  // 2 MB [4][512][512]
    unsigned short* wl  = (unsigned short*)(w8 + 18 * MB);  // 2 MB
    unsigned short* qh  = (unsigned short*)(w8 + 20 * MB);
    unsigned short* ql  = (unsigned short*)(w8 + 28 * MB);
    unsigned short* kh  = (unsigned short*)(w8 + 36 * MB);
    unsigned short* kl  = (unsigned short*)(w8 + 44 * MB);
    unsigned short* vth = (unsigned short*)(w8 + 52 * MB);
    unsigned short* vtl = (unsigned short*)(w8 + 60 * MB);  // end 68 MB
    // att (split) aliases xh/xl: x is dead once the QKV GEMMs complete.
    unsigned short* ah = xh;
    unsigned short* al = xl;
    float* out = (float*)d_out;

    conv_split<<<1024, 256, 0, stream>>>(x, xh, xl, M_ * 512 / 4);
    conv_w4<<<dim3(256, 4), 256, 0, stream>>>(Wq, Wk, Wv, Wo, wh, wl);

    // fused QKV: grid y 0-3 -> q (scaled), 4-7 -> k, 8-11 -> v (transposed)
    gemm_mfma<1><<<dim3(64, 12), 256, 0, stream>>>(xh, xl, wh, wl, nullptr, nullptr,
                                                   qh, ql, kh, kl, vth, vtl, QSCALE_);

    attn_mfma<<<dim3(N_ / 128, 16), 256, 0, stream>>>(qh, ql, kh, kl, vth, vtl, ah, al);

    // final projection + bias (13 args: nullptr oh2/ol2 added — round-6 fix)
    gemm_mfma<0><<<dim3(64, 4), 256, 0, stream>>>(ah, al, wh + 3 * 262144, wl + 3 * 262144,
                                                  bo, out, nullptr, nullptr, nullptr, nullptr,
                                                  nullptr, nullptr, 1.0f);
}

// Round 9
// 304.848 us; speedup vs baseline: 13.3406x; 1.0613x over previous
//
#include <hip/hip_runtime.h>
#include <hip/hip_bf16.h>

#define B_ 2
#define N_ 4096
#define D_ 512
#define H_ 8
#define M_ (B_*N_)              // 8192 rows
#define QSCALE_ 0.18033688011f  // 0.125 * log2(e): softmax runs in log2 domain

typedef short bf16x8 __attribute__((ext_vector_type(8)));
typedef float f32x4  __attribute__((ext_vector_type(4)));

static __device__ __forceinline__ unsigned short f2bf(float f) {
    union { float f; unsigned int u; } v; v.f = f;
    unsigned int r = v.u + 0x7fffu + ((v.u >> 16) & 1u);   // RNE
    return (unsigned short)(r >> 16);
}
static __device__ __forceinline__ float bf2f(unsigned short h) {
    union { unsigned int u; float f; } v; v.u = ((unsigned int)h) << 16;
    return v.f;
}
static __device__ __forceinline__ unsigned int cvt_pk_bf16(float a, float b) {
    unsigned int r;  // D[15:0]=bf16(a), D[31:16]=bf16(b)
    asm("v_cvt_pk_bf16_f32 %0, %1, %2" : "=v"(r) : "v"(a), "v"(b));
    return r;
}

// ---------------------------------------------------------------------------
// Merged fp32 -> split bf16 hi/lo conversion for x (1,048,576 float4) and the
// four 512x512 weights (4 x 65,536 float4). One launch.
// ---------------------------------------------------------------------------
__global__ void conv_all(const float* __restrict__ x,
                         const float* __restrict__ w0, const float* __restrict__ w1,
                         const float* __restrict__ w2, const float* __restrict__ w3,
                         unsigned short* __restrict__ xh, unsigned short* __restrict__ xl,
                         unsigned short* __restrict__ wh, unsigned short* __restrict__ wl)
{
    const int i = blockIdx.x * 256 + threadIdx.x;
    float4 v;
    ushort4* dh;
    ushort4* dl;
    if (i < 1048576) {
        v = ((const float4*)x)[i];
        dh = (ushort4*)xh + i;
        dl = (ushort4*)xl + i;
    } else {
        const int j = i - 1048576;           // 0..262143
        const int w = j >> 16, di = j & 65535;
        const float* src = w == 0 ? w0 : w == 1 ? w1 : w == 2 ? w2 : w3;
        v = ((const float4*)src)[di];
        dh = (ushort4*)(wh + (size_t)w * 262144) + di;
        dl = (ushort4*)(wl + (size_t)w * 262144) + di;
    }
    ushort4 hv, lv;
    hv.x = f2bf(v.x); hv.y = f2bf(v.y); hv.z = f2bf(v.z); hv.w = f2bf(v.w);
    lv.x = f2bf(v.x - bf2f(hv.x)); lv.y = f2bf(v.y - bf2f(hv.y));
    lv.z = f2bf(v.z - bf2f(hv.z)); lv.w = f2bf(v.w - bf2f(hv.w));
    *dh = hv;
    *dl = lv;
}

// ---------------------------------------------------------------------------
// Split-bf16 MFMA GEMM: Y = A @ W^T (3-term). Tile 128x128, BK=32, 4 waves.
// MODE 0: fp32 out + bias. MODE 1: fused QKV (y 0-3 q / 4-7 k / 8-11 v^T;
// v writes hi plane only — attention PV no longer uses the V residual).
// ---------------------------------------------------------------------------
template<int MODE>
__global__ __launch_bounds__(256, 2) void gemm_mfma(
    const unsigned short* __restrict__ Ah, const unsigned short* __restrict__ Al,
    const unsigned short* __restrict__ Wh, const unsigned short* __restrict__ Wl,
    const float* __restrict__ bias, float* __restrict__ outF,
    unsigned short* __restrict__ oh0, unsigned short* __restrict__ ol0,
    unsigned short* __restrict__ oh1, unsigned short* __restrict__ ol1,
    unsigned short* __restrict__ oh2, unsigned short* __restrict__ ol2,
    float scale0)
{
    __shared__ unsigned short At[2][8192];   // [buf][row*64 + swz-chunk*8]
    __shared__ unsigned short Bt[2][8192];

    const int t = threadIdx.x;
    const int lane = t & 63, wave = t >> 6;
    const int l15 = lane & 15, g = lane >> 4;
    const int wr = wave >> 1, wc = wave & 1;
    const int mb = blockIdx.x * 128;

    int which = 0, nbeff;
    if (MODE == 1) { which = blockIdx.y >> 2; nbeff = (blockIdx.y & 3) * 128; }
    else           { nbeff = blockIdx.y * 128; }
    const unsigned short* Whp = Wh + (size_t)which * 262144;
    const unsigned short* Wlp = Wl + (size_t)which * 262144;

    const int srow = t >> 1, sh = t & 1;
    const size_t gAr = (size_t)(mb + srow) * 512 + sh * 16;
    const size_t gBr = (size_t)(nbeff + srow) * 512 + sh * 16;
    const int sw = srow & 7;
    const int dA0 = srow * 64 + (((sh * 2 + 0) ^ sw) * 8);
    const int dA1 = srow * 64 + (((sh * 2 + 1) ^ sw) * 8);
    const int dA2 = srow * 64 + (((sh * 2 + 4) ^ sw) * 8);
    const int dA3 = srow * 64 + (((sh * 2 + 5) ^ sw) * 8);

    bf16x8 sA[4], sB[4];
#define GLOAD(K0) do {                                                              \
        sA[0] = *(const bf16x8*)&Ah[gAr + (K0)];  sA[1] = *(const bf16x8*)&Ah[gAr + (K0) + 8];  \
        sA[2] = *(const bf16x8*)&Al[gAr + (K0)];  sA[3] = *(const bf16x8*)&Al[gAr + (K0) + 8];  \
        sB[0] = *(const bf16x8*)&Whp[gBr + (K0)]; sB[1] = *(const bf16x8*)&Whp[gBr + (K0) + 8]; \
        sB[2] = *(const bf16x8*)&Wlp[gBr + (K0)]; sB[3] = *(const bf16x8*)&Wlp[gBr + (K0) + 8]; \
    } while (0)
#define SWRITE(BB) do {                                                             \
        *(bf16x8*)&At[BB][dA0] = sA[0]; *(bf16x8*)&At[BB][dA1] = sA[1];             \
        *(bf16x8*)&At[BB][dA2] = sA[2]; *(bf16x8*)&At[BB][dA3] = sA[3];             \
        *(bf16x8*)&Bt[BB][dA0] = sB[0]; *(bf16x8*)&Bt[BB][dA1] = sB[1];             \
        *(bf16x8*)&Bt[BB][dA2] = sB[2]; *(bf16x8*)&Bt[BB][dA3] = sB[3];             \
    } while (0)

    f32x4 acc[4][4];
#pragma unroll
    for (int mi = 0; mi < 4; ++mi)
#pragma unroll
        for (int ni = 0; ni < 4; ++ni) acc[mi][ni] = (f32x4){0.f, 0.f, 0.f, 0.f};

    GLOAD(0); SWRITE(0); __syncthreads();
    int cur = 0;
    for (int ks = 0; ks < 16; ++ks) {
        if (ks < 15) GLOAD((ks + 1) * 32);

        bf16x8 afh[4], afl[4], wfh[4], wfl[4];
#pragma unroll
        for (int mi = 0; mi < 4; ++mi) {
            const int ar = wr * 64 + mi * 16 + l15, asw = ar & 7;
            afh[mi] = *(const bf16x8*)&At[cur][ar * 64 + ((g ^ asw) * 8)];
            afl[mi] = *(const bf16x8*)&At[cur][ar * 64 + (((g + 4) ^ asw) * 8)];
        }
#pragma unroll
        for (int ni = 0; ni < 4; ++ni) {
            const int br = wc * 64 + ni * 16 + l15, bsw = br & 7;
            wfh[ni] = *(const bf16x8*)&Bt[cur][br * 64 + ((g ^ bsw) * 8)];
            wfl[ni] = *(const bf16x8*)&Bt[cur][br * 64 + (((g + 4) ^ bsw) * 8)];
        }
#pragma unroll
        for (int mi = 0; mi < 4; ++mi)
#pragma unroll
            for (int ni = 0; ni < 4; ++ni) {
                acc[mi][ni] = __builtin_amdgcn_mfma_f32_16x16x32_bf16(afh[mi], wfh[ni], acc[mi][ni], 0, 0, 0);
                acc[mi][ni] = __builtin_amdgcn_mfma_f32_16x16x32_bf16(afl[mi], wfh[ni], acc[mi][ni], 0, 0, 0);
                acc[mi][ni] = __builtin_amdgcn_mfma_f32_16x16x32_bf16(afh[mi], wfl[ni], acc[mi][ni], 0, 0, 0);
            }

        if (ks < 15) SWRITE(cur ^ 1);
        __syncthreads();
        cur ^= 1;
    }
#undef GLOAD
#undef SWRITE

    if (MODE == 0) {
#pragma unroll
        for (int ni = 0; ni < 4; ++ni) {
            const int col = nbeff + wc * 64 + ni * 16 + l15;
            const float bv = bias[col];
#pragma unroll
            for (int mi = 0; mi < 4; ++mi) {
                const int m0 = mb + wr * 64 + mi * 16 + g * 4;
#pragma unroll
                for (int r = 0; r < 4; ++r)
                    outF[(size_t)(m0 + r) * 512 + col] = acc[mi][ni][r] + bv;
            }
        }
    } else if (which < 2) {   // q or k: split [bh][seq][64]
        unsigned short* oh = which ? oh1 : oh0;
        unsigned short* ol = which ? ol1 : ol0;
        const float scl = which ? 1.0f : scale0;
#pragma unroll
        for (int ni = 0; ni < 4; ++ni) {
            const int col = nbeff + wc * 64 + ni * 16 + l15;
            const int hh = col >> 6, dd = col & 63;
#pragma unroll
            for (int mi = 0; mi < 4; ++mi) {
                const int m0 = mb + wr * 64 + mi * 16 + g * 4;
                const int b = m0 >> 12, seq0 = m0 & (N_ - 1);
                const size_t base = ((size_t)(b * H_ + hh) * N_ + seq0) * 64 + dd;
#pragma unroll
                for (int r = 0; r < 4; ++r) {
                    const float s = acc[mi][ni][r] * scl;
                    const unsigned short hv = f2bf(s);
                    oh[base + (size_t)r * 64] = hv;
                    ol[base + (size_t)r * 64] = f2bf(s - bf2f(hv));
                }
            }
        }
    } else {  // v: hi plane only, transposed [bh][64][4096]
#pragma unroll
        for (int ni = 0; ni < 4; ++ni) {
            const int col = nbeff + wc * 64 + ni * 16 + l15;
            const int hh = col >> 6, dd = col & 63;
#pragma unroll
            for (int mi = 0; mi < 4; ++mi) {
                const int m0 = mb + wr * 64 + mi * 16 + g * 4;
                const int b = m0 >> 12, seq0 = m0 & (N_ - 1);
                const size_t base = ((size_t)((b * H_ + hh) * 64) + dd) * N_ + seq0;
                ushort4 hv;
                hv.x = f2bf(acc[mi][ni][0]); hv.y = f2bf(acc[mi][ni][1]);
                hv.z = f2bf(acc[mi][ni][2]); hv.w = f2bf(acc[mi][ni][3]);
                *(ushort4*)&oh2[base] = hv;
            }
        }
    }
}

// ---------------------------------------------------------------------------
// Flash attention, two-tile pipeline (T15): iteration t runs QK^T(t) [MFMA]
// source-interleaved with softmax(t-1) [VALU], then PV(t-1). Two S states
// (Sa even tiles, Sb odd). PV is single-term Vh*Ph (V residual dropped; same
// error class as the validated P-residual drop). LDS 48KB: K hi/lo dbuf +
// V hi dbuf. Buffer safety: PV(t-1) reads Vb[(t-1)&1]; WRITET(t+1) overwrites
// it -> barrier between PV and WRITET, second barrier after WRITET.
// K staged with permuted rows rho(n) so S^T output = PV B-fragment layout
// (validated round 4). QK^T stays 3-term. Defer-max (thr=8, log2 domain).
// ---------------------------------------------------------------------------
__global__ __launch_bounds__(256, 2) void attn_mfma(
    const unsigned short* __restrict__ qh, const unsigned short* __restrict__ ql,
    const unsigned short* __restrict__ kh, const unsigned short* __restrict__ kl,
    const unsigned short* __restrict__ vth,
    unsigned short* __restrict__ oh, unsigned short* __restrict__ ol)
{
    __shared__ unsigned short Kb[2][2][4096];   // [buf][hi/lo][perm-row*64 + swz]
    __shared__ unsigned short Vb[2][4096];      // [buf][d-row*64 + swz]

    const int t    = threadIdx.x;
    const int lane = t & 63;
    const int wave = t >> 6;
    const int l15  = lane & 15;
    const int g    = lane >> 4;
    const int bh   = blockIdx.y;
    const int qbase = blockIdx.x * 128 + wave * 32;

    bf16x8 qf[2][2][2];   // [rowtile][chunk][hi/lo]
#pragma unroll
    for (int rt = 0; rt < 2; ++rt)
#pragma unroll
        for (int c = 0; c < 2; ++c) {
            const size_t src = ((size_t)bh * N_ + qbase + rt * 16 + l15) * 64 + c * 32 + g * 8;
            qf[rt][c][0] = *(const bf16x8*)&qh[src];
            qf[rt][c][1] = *(const bf16x8*)&ql[src];
        }

    f32x4 O[2][4];
#pragma unroll
    for (int rt = 0; rt < 2; ++rt)
#pragma unroll
        for (int dt = 0; dt < 4; ++dt) O[rt][dt] = (f32x4){0.f, 0.f, 0.f, 0.f};
    float mreg[2] = {-3.0e38f, -3.0e38f};
    float lreg[2] = {0.f, 0.f};

    const int srow = t >> 3;          // 0..31
    const int sc16 = t & 7;
    const size_t kbase = (size_t)bh * N_ * 64;
    const size_t vbase = (size_t)bh * 64 * N_;
    const int vdst0 = srow * 64 + ((sc16 ^ (srow & 7)) * 8);
    const int vdst1 = (srow + 32) * 64 + ((sc16 ^ ((srow + 32) & 7)) * 8);
    const int krho  = (((srow >> 2) & 1) << 4) | (((srow >> 3) & 3) << 2) | (srow & 3);
    const int kdst0 = krho * 64 + ((sc16 ^ (krho & 7)) * 8);
    const int kdst1 = kdst0 + 32 * 64;

    bf16x8 sKh[2], sKl[2], sVh[2];

#define LOADT(KT) do {                                                                \
        const size_t gK0 = kbase + ((size_t)((KT) * 64 + srow)) * 64 + sc16 * 8;      \
        const size_t gK1 = kbase + ((size_t)((KT) * 64 + srow + 32)) * 64 + sc16 * 8; \
        const size_t gV0 = vbase + (size_t)srow * N_ + (KT) * 64 + sc16 * 8;          \
        const size_t gV1 = vbase + (size_t)(srow + 32) * N_ + (KT) * 64 + sc16 * 8;   \
        sKh[0] = *(const bf16x8*)&kh[gK0];  sKh[1] = *(const bf16x8*)&kh[gK1];        \
        sKl[0] = *(const bf16x8*)&kl[gK0];  sKl[1] = *(const bf16x8*)&kl[gK1];        \
        sVh[0] = *(const bf16x8*)&vth[gV0]; sVh[1] = *(const bf16x8*)&vth[gV1];       \
    } while (0)

#define WRITET(BB) do {                                                               \
        *(bf16x8*)&Kb[BB][0][kdst0] = sKh[0]; *(bf16x8*)&Kb[BB][0][kdst1] = sKh[1];   \
        *(bf16x8*)&Kb[BB][1][kdst0] = sKl[0]; *(bf16x8*)&Kb[BB][1][kdst1] = sKl[1];   \
        *(bf16x8*)&Vb[BB][vdst0] = sVh[0];    *(bf16x8*)&Vb[BB][vdst1] = sVh[1];      \
    } while (0)

// QK^T j-tile (3-term) into S from Kb[BUF]
#define QKT_J(J, BUF, S) do {                                                         \
        const int krow_ = (J) * 16 + l15;                                             \
        const int rb_ = krow_ * 64, sw_ = (krow_ & 7) * 8;                            \
        _Pragma("unroll")                                                             \
        for (int c = 0; c < 2; ++c) {                                                 \
            const int off_ = rb_ + (((c * 4 + g) * 8) ^ sw_);                         \
            bf16x8 kfh_ = *(const bf16x8*)&Kb[BUF][0][off_];                          \
            bf16x8 kfl_ = *(const bf16x8*)&Kb[BUF][1][off_];                          \
            _Pragma("unroll")                                                         \
            for (int rt = 0; rt < 2; ++rt) {                                          \
                S[rt][J] = __builtin_amdgcn_mfma_f32_16x16x32_bf16(kfh_, qf[rt][c][0], S[rt][J], 0, 0, 0); \
                S[rt][J] = __builtin_amdgcn_mfma_f32_16x16x32_bf16(kfl_, qf[rt][c][0], S[rt][J], 0, 0, 0); \
                S[rt][J] = __builtin_amdgcn_mfma_f32_16x16x32_bf16(kfh_, qf[rt][c][1], S[rt][J], 0, 0, 0); \
            }                                                                         \
        }                                                                             \
    } while (0)

// online softmax for row-tile RT of state S -> pah fragments (log2 domain)
#define SOFTMAX_RT(RT, S) do {                                                        \
        float pmax_ = -3.0e38f;                                                       \
        _Pragma("unroll")                                                             \
        for (int j = 0; j < 4; ++j)                                                   \
            _Pragma("unroll")                                                         \
            for (int r = 0; r < 4; ++r) pmax_ = fmaxf(pmax_, S[RT][j][r]);            \
        pmax_ = fmaxf(pmax_, __shfl_xor(pmax_, 16));                                  \
        pmax_ = fmaxf(pmax_, __shfl_xor(pmax_, 32));                                  \
        const float mold_ = mreg[RT];                                                 \
        if (!__all(pmax_ <= mold_ + 8.0f)) {                                          \
            const float mnew_ = fmaxf(mold_, pmax_);                                  \
            const float alpha_ = exp2f(mold_ - mnew_);                                \
            _Pragma("unroll")                                                         \
            for (int dt = 0; dt < 4; ++dt)                                            \
                _Pragma("unroll")                                                     \
                for (int r = 0; r < 4; ++r) O[RT][dt][r] *= alpha_;                   \
            lreg[RT] *= alpha_;                                                       \
            mreg[RT] = mnew_;                                                         \
        }                                                                             \
        const float mb_ = mreg[RT];                                                   \
        float lsum_ = 0.f;                                                            \
        _Pragma("unroll")                                                             \
        for (int j = 0; j < 4; ++j)                                                   \
            _Pragma("unroll")                                                         \
            for (int r = 0; r < 4; ++r) {                                             \
                S[RT][j][r] = exp2f(S[RT][j][r] - mb_);                               \
                lsum_ += S[RT][j][r];                                                 \
            }                                                                         \
        lreg[RT] += lsum_;                                                            \
        _Pragma("unroll")                                                             \
        for (int c = 0; c < 2; ++c) {                                                 \
            union { unsigned int u[4]; bf16x8 v; } th_;                               \
            th_.u[0] = cvt_pk_bf16(S[RT][2*c][0], S[RT][2*c][1]);                     \
            th_.u[1] = cvt_pk_bf16(S[RT][2*c][2], S[RT][2*c][3]);                     \
            th_.u[2] = cvt_pk_bf16(S[RT][2*c+1][0], S[RT][2*c+1][1]);                 \
            th_.u[3] = cvt_pk_bf16(S[RT][2*c+1][2], S[RT][2*c+1][3]);                 \
            pah[RT][c] = th_.v;                                                       \
        }                                                                             \
    } while (0)

// PV single-term: O += Vh[BUF] . P^T
#define PVSTEP(BUF) do {                                                              \
        _Pragma("unroll")                                                             \
        for (int c = 0; c < 2; ++c)                                                   \
            _Pragma("unroll")                                                         \
            for (int dt = 0; dt < 4; ++dt) {                                          \
                const int vrow_ = dt * 16 + l15;                                      \
                const int off_ = vrow_ * 64 + (((c * 4 + g) * 8) ^ ((vrow_ & 7) * 8));\
                bf16x8 vfh_ = *(const bf16x8*)&Vb[BUF][off_];                         \
                _Pragma("unroll")                                                     \
                for (int rt = 0; rt < 2; ++rt)                                        \
                    O[rt][dt] = __builtin_amdgcn_mfma_f32_16x16x32_bf16(vfh_, pah[rt][c], O[rt][dt], 0, 0, 0); \
            }                                                                         \
    } while (0)

// one pipeline iteration: QK^T(T) into SC, finish tile T-1 from SP
#define ITER(T, BK, SC, SP) do {                                                      \
        if ((T) < 63) LOADT((T) + 1);                                                 \
        __builtin_amdgcn_s_setprio(1);                                                \
        SC[0][0] = (f32x4){0.f,0.f,0.f,0.f}; SC[0][1] = (f32x4){0.f,0.f,0.f,0.f};     \
        SC[0][2] = (f32x4){0.f,0.f,0.f,0.f}; SC[0][3] = (f32x4){0.f,0.f,0.f,0.f};     \
        SC[1][0] = (f32x4){0.f,0.f,0.f,0.f}; SC[1][1] = (f32x4){0.f,0.f,0.f,0.f};     \
        SC[1][2] = (f32x4){0.f,0.f,0.f,0.f}; SC[1][3] = (f32x4){0.f,0.f,0.f,0.f};     \
        QKT_J(0, BK, SC); QKT_J(1, BK, SC);                                           \
        SOFTMAX_RT(0, SP);                                                            \
        QKT_J(2, BK, SC); QKT_J(3, BK, SC);                                           \
        SOFTMAX_RT(1, SP);                                                            \
        PVSTEP((BK) ^ 1);                                                             \
        __builtin_amdgcn_s_setprio(0);                                                \
        __syncthreads();                                                              \
        if ((T) < 63) WRITET((BK) ^ 1);                                               \
        __syncthreads();                                                              \
    } while (0)

    f32x4 Sa[2][4], Sb[2][4];
    bf16x8 pah[2][2];

    // prologue: tile 0 staged + QK^T(0); tile 1 staged behind it
    LOADT(0); WRITET(0); __syncthreads();
    LOADT(1);
#pragma unroll
    for (int rt = 0; rt < 2; ++rt)
#pragma unroll
        for (int j = 0; j < 4; ++j) Sa[rt][j] = (f32x4){0.f, 0.f, 0.f, 0.f};
    __builtin_amdgcn_s_setprio(1);
    QKT_J(0, 0, Sa); QKT_J(1, 0, Sa); QKT_J(2, 0, Sa); QKT_J(3, 0, Sa);
    __builtin_amdgcn_s_setprio(0);
    WRITET(1);
    __syncthreads();

    for (int tt = 1; tt < 64; tt += 2) {
        ITER(tt, 1, Sb, Sa);                       // odd tile -> Sb, finish Sa
        if (tt + 1 < 64) ITER(tt + 1, 0, Sa, Sb);  // even tile -> Sa, finish Sb
    }
    // drain tile 63 (odd -> Sb; its V tile sits in Vb[1])
    SOFTMAX_RT(0, Sb);
    SOFTMAX_RT(1, Sb);
    PVSTEP(1);

    // ---- epilogue: normalize, split to bf16 hi/lo, write [b n][h*64+d] ----
    const int b = bh >> 3, hh = bh & 7;
#pragma unroll
    for (int rt = 0; rt < 2; ++rt) {
        float lt = lreg[rt];
        lt += __shfl_xor(lt, 16);
        lt += __shfl_xor(lt, 32);
        const float inv = 1.0f / lt;
        const int n = qbase + rt * 16 + l15;
        const size_t rowbase = ((size_t)(b * N_) + n) * 512 + hh * 64 + g * 4;
#pragma unroll
        for (int dt = 0; dt < 4; ++dt) {
            const float s0 = O[rt][dt][0] * inv, s1 = O[rt][dt][1] * inv,
                        s2 = O[rt][dt][2] * inv, s3 = O[rt][dt][3] * inv;
            ushort4 hv, lv;
            hv.x = f2bf(s0); hv.y = f2bf(s1); hv.z = f2bf(s2); hv.w = f2bf(s3);
            lv.x = f2bf(s0 - bf2f(hv.x)); lv.y = f2bf(s1 - bf2f(hv.y));
            lv.z = f2bf(s2 - bf2f(hv.z)); lv.w = f2bf(s3 - bf2f(hv.w));
            *(ushort4*)&oh[rowbase + dt * 16] = hv;
            *(ushort4*)&ol[rowbase + dt * 16] = lv;
        }
    }
#undef LOADT
#undef WRITET
#undef QKT_J
#undef SOFTMAX_RT
#undef PVSTEP
#undef ITER
}

// ---------------------------------------------------------------------------
extern "C" void kernel_launch(void* const* d_in, const int* in_sizes, int n_in,
                              void* d_out, int out_size, void* d_ws, size_t ws_size,
                              hipStream_t stream)
{
    const float* x  = (const float*)d_in[0];
    const float* Wq = (const float*)d_in[1];
    const float* Wk = (const float*)d_in[2];
    const float* Wv = (const float*)d_in[3];
    const float* Wo = (const float*)d_in[4];
    const float* bo = (const float*)d_in[5];

    unsigned char* w8 = (unsigned char*)d_ws;
    const size_t MB = 1024 * 1024;
    unsigned short* xh  = (unsigned short*)(w8);            // 8 MB
    unsigned short* xl  = (unsigned short*)(w8 + 8  * MB);  // 8 MB
    unsigned short* wh  = (unsigned short*)(w8 + 16 * MB);  // 2 MB [4][512][512]
    unsigned short* wl  = (unsigned short*)(w8 + 18 * MB);  // 2 MB
    unsigned short* qh  = (unsigned short*)(w8 + 20 * MB);
    unsigned short* ql  = (unsigned short*)(w8 + 28 * MB);
    unsigned short* kh  = (unsigned short*)(w8 + 36 * MB);
    unsigned short* kl  = (unsigned short*)(w8 + 44 * MB);
    unsigned short* vth = (unsigned short*)(w8 + 52 * MB);  // end 60 MB
    // att (split) aliases xh/xl: x is dead once the QKV GEMMs complete.
    unsigned short* ah = xh;
    unsigned short* al = xl;
    float* out = (float*)d_out;

    conv_all<<<5120, 256, 0, stream>>>(x, Wq, Wk, Wv, Wo, xh, xl, wh, wl);

    // fused QKV: grid y 0-3 -> q (scaled), 4-7 -> k, 8-11 -> v (hi, transposed)
    gemm_mfma<1><<<dim3(64, 12), 256, 0, stream>>>(xh, xl, wh, wl, nullptr, nullptr,
                                                   qh, ql, kh, kl, vth, nullptr, QSCALE_);

    attn_mfma<<<dim3(N_ / 128, 16), 256, 0, stream>>>(qh, ql, kh, kl, vth, ah, al);

    // final projection + bias
    gemm_mfma<0><<<dim3(64, 4), 256, 0, stream>>>(ah, al, wh + 3 * 262144, wl + 3 * 262144,
                                                  bo, out, nullptr, nullptr, nullptr, nullptr,
                                                  nullptr, nullptr, 1.0f);
}

// Round 10
// 304.246 us; speedup vs baseline: 13.3670x; 1.0020x over previous
//
#include <hip/hip_runtime.h>
#include <hip/hip_bf16.h>

#define B_ 2
#define N_ 4096
#define D_ 512
#define H_ 8
#define M_ (B_*N_)              // 8192 rows
#define QSCALE_ 0.18033688011f  // 0.125 * log2(e): softmax runs in log2 domain

typedef short bf16x8 __attribute__((ext_vector_type(8)));
typedef float f32x4  __attribute__((ext_vector_type(4)));

static __device__ __forceinline__ unsigned short f2bf(float f) {
    union { float f; unsigned int u; } v; v.f = f;
    unsigned int r = v.u + 0x7fffu + ((v.u >> 16) & 1u);   // RNE
    return (unsigned short)(r >> 16);
}
static __device__ __forceinline__ float bf2f(unsigned short h) {
    union { unsigned int u; float f; } v; v.u = ((unsigned int)h) << 16;
    return v.f;
}
static __device__ __forceinline__ unsigned int cvt_pk_bf16(float a, float b) {
    unsigned int r;  // D[15:0]=bf16(a), D[31:16]=bf16(b)
    asm("v_cvt_pk_bf16_f32 %0, %1, %2" : "=v"(r) : "v"(a), "v"(b));
    return r;
}

// ---------------------------------------------------------------------------
// Merged fp32 -> split bf16 hi/lo conversion for x (1,048,576 float4) and the
// four 512x512 weights (4 x 65,536 float4). One launch.
// ---------------------------------------------------------------------------
__global__ void conv_all(const float* __restrict__ x,
                         const float* __restrict__ w0, const float* __restrict__ w1,
                         const float* __restrict__ w2, const float* __restrict__ w3,
                         unsigned short* __restrict__ xh, unsigned short* __restrict__ xl,
                         unsigned short* __restrict__ wh, unsigned short* __restrict__ wl)
{
    const int i = blockIdx.x * 256 + threadIdx.x;
    float4 v;
    ushort4* dh;
    ushort4* dl;
    if (i < 1048576) {
        v = ((const float4*)x)[i];
        dh = (ushort4*)xh + i;
        dl = (ushort4*)xl + i;
    } else {
        const int j = i - 1048576;           // 0..262143
        const int w = j >> 16, di = j & 65535;
        const float* src = w == 0 ? w0 : w == 1 ? w1 : w == 2 ? w2 : w3;
        v = ((const float4*)src)[di];
        dh = (ushort4*)(wh + (size_t)w * 262144) + di;
        dl = (ushort4*)(wl + (size_t)w * 262144) + di;
    }
    ushort4 hv, lv;
    hv.x = f2bf(v.x); hv.y = f2bf(v.y); hv.z = f2bf(v.z); hv.w = f2bf(v.w);
    lv.x = f2bf(v.x - bf2f(hv.x)); lv.y = f2bf(v.y - bf2f(hv.y));
    lv.z = f2bf(v.z - bf2f(hv.z)); lv.w = f2bf(v.w - bf2f(hv.w));
    *dh = hv;
    *dl = lv;
}

// ---------------------------------------------------------------------------
// Split-bf16 MFMA GEMM: Y = A @ W^T (3-term). Tile 128x128, BK=32, 4 waves.
// MODE 0: fp32 out + bias. MODE 1: fused QKV (y 0-3 q / 4-7 k / 8-11 v^T;
// v writes hi plane only).
// ---------------------------------------------------------------------------
template<int MODE>
__global__ __launch_bounds__(256, 2) void gemm_mfma(
    const unsigned short* __restrict__ Ah, const unsigned short* __restrict__ Al,
    const unsigned short* __restrict__ Wh, const unsigned short* __restrict__ Wl,
    const float* __restrict__ bias, float* __restrict__ outF,
    unsigned short* __restrict__ oh0, unsigned short* __restrict__ ol0,
    unsigned short* __restrict__ oh1, unsigned short* __restrict__ ol1,
    unsigned short* __restrict__ oh2, unsigned short* __restrict__ ol2,
    float scale0)
{
    __shared__ unsigned short At[2][8192];   // [buf][row*64 + swz-chunk*8]
    __shared__ unsigned short Bt[2][8192];

    const int t = threadIdx.x;
    const int lane = t & 63, wave = t >> 6;
    const int l15 = lane & 15, g = lane >> 4;
    const int wr = wave >> 1, wc = wave & 1;
    const int mb = blockIdx.x * 128;

    int which = 0, nbeff;
    if (MODE == 1) { which = blockIdx.y >> 2; nbeff = (blockIdx.y & 3) * 128; }
    else           { nbeff = blockIdx.y * 128; }
    const unsigned short* Whp = Wh + (size_t)which * 262144;
    const unsigned short* Wlp = Wl + (size_t)which * 262144;

    const int srow = t >> 1, sh = t & 1;
    const size_t gAr = (size_t)(mb + srow) * 512 + sh * 16;
    const size_t gBr = (size_t)(nbeff + srow) * 512 + sh * 16;
    const int sw = srow & 7;
    const int dA0 = srow * 64 + (((sh * 2 + 0) ^ sw) * 8);
    const int dA1 = srow * 64 + (((sh * 2 + 1) ^ sw) * 8);
    const int dA2 = srow * 64 + (((sh * 2 + 4) ^ sw) * 8);
    const int dA3 = srow * 64 + (((sh * 2 + 5) ^ sw) * 8);

    bf16x8 sA[4], sB[4];
#define GLOAD(K0) do {                                                              \
        sA[0] = *(const bf16x8*)&Ah[gAr + (K0)];  sA[1] = *(const bf16x8*)&Ah[gAr + (K0) + 8];  \
        sA[2] = *(const bf16x8*)&Al[gAr + (K0)];  sA[3] = *(const bf16x8*)&Al[gAr + (K0) + 8];  \
        sB[0] = *(const bf16x8*)&Whp[gBr + (K0)]; sB[1] = *(const bf16x8*)&Whp[gBr + (K0) + 8]; \
        sB[2] = *(const bf16x8*)&Wlp[gBr + (K0)]; sB[3] = *(const bf16x8*)&Wlp[gBr + (K0) + 8]; \
    } while (0)
#define SWRITE(BB) do {                                                             \
        *(bf16x8*)&At[BB][dA0] = sA[0]; *(bf16x8*)&At[BB][dA1] = sA[1];             \
        *(bf16x8*)&At[BB][dA2] = sA[2]; *(bf16x8*)&At[BB][dA3] = sA[3];             \
        *(bf16x8*)&Bt[BB][dA0] = sB[0]; *(bf16x8*)&Bt[BB][dA1] = sB[1];             \
        *(bf16x8*)&Bt[BB][dA2] = sB[2]; *(bf16x8*)&Bt[BB][dA3] = sB[3];             \
    } while (0)

    f32x4 acc[4][4];
#pragma unroll
    for (int mi = 0; mi < 4; ++mi)
#pragma unroll
        for (int ni = 0; ni < 4; ++ni) acc[mi][ni] = (f32x4){0.f, 0.f, 0.f, 0.f};

    GLOAD(0); SWRITE(0); __syncthreads();
    int cur = 0;
    for (int ks = 0; ks < 16; ++ks) {
        if (ks < 15) GLOAD((ks + 1) * 32);

        bf16x8 afh[4], afl[4], wfh[4], wfl[4];
#pragma unroll
        for (int mi = 0; mi < 4; ++mi) {
            const int ar = wr * 64 + mi * 16 + l15, asw = ar & 7;
            afh[mi] = *(const bf16x8*)&At[cur][ar * 64 + ((g ^ asw) * 8)];
            afl[mi] = *(const bf16x8*)&At[cur][ar * 64 + (((g + 4) ^ asw) * 8)];
        }
#pragma unroll
        for (int ni = 0; ni < 4; ++ni) {
            const int br = wc * 64 + ni * 16 + l15, bsw = br & 7;
            wfh[ni] = *(const bf16x8*)&Bt[cur][br * 64 + ((g ^ bsw) * 8)];
            wfl[ni] = *(const bf16x8*)&Bt[cur][br * 64 + (((g + 4) ^ bsw) * 8)];
        }
#pragma unroll
        for (int mi = 0; mi < 4; ++mi)
#pragma unroll
            for (int ni = 0; ni < 4; ++ni) {
                acc[mi][ni] = __builtin_amdgcn_mfma_f32_16x16x32_bf16(afh[mi], wfh[ni], acc[mi][ni], 0, 0, 0);
                acc[mi][ni] = __builtin_amdgcn_mfma_f32_16x16x32_bf16(afl[mi], wfh[ni], acc[mi][ni], 0, 0, 0);
                acc[mi][ni] = __builtin_amdgcn_mfma_f32_16x16x32_bf16(afh[mi], wfl[ni], acc[mi][ni], 0, 0, 0);
            }

        if (ks < 15) SWRITE(cur ^ 1);
        __syncthreads();
        cur ^= 1;
    }
#undef GLOAD
#undef SWRITE

    if (MODE == 0) {
#pragma unroll
        for (int ni = 0; ni < 4; ++ni) {
            const int col = nbeff + wc * 64 + ni * 16 + l15;
            const float bv = bias[col];
#pragma unroll
            for (int mi = 0; mi < 4; ++mi) {
                const int m0 = mb + wr * 64 + mi * 16 + g * 4;
#pragma unroll
                for (int r = 0; r < 4; ++r)
                    outF[(size_t)(m0 + r) * 512 + col] = acc[mi][ni][r] + bv;
            }
        }
    } else if (which < 2) {   // q or k: split [bh][seq][64]
        unsigned short* oh = which ? oh1 : oh0;
        unsigned short* ol = which ? ol1 : ol0;
        const float scl = which ? 1.0f : scale0;
#pragma unroll
        for (int ni = 0; ni < 4; ++ni) {
            const int col = nbeff + wc * 64 + ni * 16 + l15;
            const int hh = col >> 6, dd = col & 63;
#pragma unroll
            for (int mi = 0; mi < 4; ++mi) {
                const int m0 = mb + wr * 64 + mi * 16 + g * 4;
                const int b = m0 >> 12, seq0 = m0 & (N_ - 1);
                const size_t base = ((size_t)(b * H_ + hh) * N_ + seq0) * 64 + dd;
#pragma unroll
                for (int r = 0; r < 4; ++r) {
                    const float s = acc[mi][ni][r] * scl;
                    const unsigned short hv = f2bf(s);
                    oh[base + (size_t)r * 64] = hv;
                    ol[base + (size_t)r * 64] = f2bf(s - bf2f(hv));
                }
            }
        }
    } else {  // v: hi plane only, transposed [bh][64][4096]
#pragma unroll
        for (int ni = 0; ni < 4; ++ni) {
            const int col = nbeff + wc * 64 + ni * 16 + l15;
            const int hh = col >> 6, dd = col & 63;
#pragma unroll
            for (int mi = 0; mi < 4; ++mi) {
                const int m0 = mb + wr * 64 + mi * 16 + g * 4;
                const int b = m0 >> 12, seq0 = m0 & (N_ - 1);
                const size_t base = ((size_t)((b * H_ + hh) * 64) + dd) * N_ + seq0;
                ushort4 hv;
                hv.x = f2bf(acc[mi][ni][0]); hv.y = f2bf(acc[mi][ni][1]);
                hv.z = f2bf(acc[mi][ni][2]); hv.w = f2bf(acc[mi][ni][3]);
                *(ushort4*)&oh2[base] = hv;
            }
        }
    }
}

// ---------------------------------------------------------------------------
// Flash attention, 8-wave blocks (512 thr), 16 q-rows per wave: grid stays
// 2 blocks/CU but occupancy doubles to 4 waves/SIMD so one wave's MFMA burst
// overlaps another's softmax VALU burst (the round-9 latency diagnosis).
// K/V LDS tiles (48 KB, shared per block) now amortize over 8 waves; each
// thread stages 3x16B per tile. T15 two-tile pipeline, permuted-K staging
// (S^T output = PV B-frag layout), single-term PV, defer-max — all carried
// over from the validated round-9 kernel; arithmetic unchanged.
// ---------------------------------------------------------------------------
__global__ __launch_bounds__(512, 4) void attn_mfma(
    const unsigned short* __restrict__ qh, const unsigned short* __restrict__ ql,
    const unsigned short* __restrict__ kh, const unsigned short* __restrict__ kl,
    const unsigned short* __restrict__ vth,
    unsigned short* __restrict__ oh, unsigned short* __restrict__ ol)
{
    __shared__ unsigned short Kb[2][2][4096];   // [buf][hi/lo][perm-row*64 + swz]
    __shared__ unsigned short Vb[2][4096];      // [buf][d-row*64 + swz]

    const int t    = threadIdx.x;
    const int lane = t & 63;
    const int wave = t >> 6;                    // 0..7
    const int l15  = lane & 15;
    const int g    = lane >> 4;
    const int bh   = blockIdx.y;
    const int qbase = blockIdx.x * 128 + wave * 16;

    // Q B-fragments: lane(l15,g) holds Q[qrow=l15][d = c*32+g*8+i]
    bf16x8 qf[2][2];   // [chunk][hi/lo]
#pragma unroll
    for (int c = 0; c < 2; ++c) {
        const size_t src = ((size_t)bh * N_ + qbase + l15) * 64 + c * 32 + g * 8;
        qf[c][0] = *(const bf16x8*)&qh[src];
        qf[c][1] = *(const bf16x8*)&ql[src];
    }

    f32x4 O[4];        // O^T: lane holds qrow=l15, d = dt*16 + g*4 + r
#pragma unroll
    for (int dt = 0; dt < 4; ++dt) O[dt] = (f32x4){0.f, 0.f, 0.f, 0.f};
    float mreg = -3.0e38f, lreg = 0.f;

    // staging: 512 threads cover a full 64x64 bf16 plane in one slot each
    const int srow = t >> 3;          // 0..63
    const int sc16 = t & 7;           // 0..7
    const size_t kbase = (size_t)bh * N_ * 64;
    const size_t vbase = (size_t)bh * 64 * N_;
    const int vdst = srow * 64 + ((sc16 ^ (srow & 7)) * 8);
    const int krho = ((srow >> 5) << 5) | (((srow >> 2) & 1) << 4)
                   | (((srow >> 3) & 3) << 2) | (srow & 3);
    const int kdst = krho * 64 + ((sc16 ^ (krho & 7)) * 8);

    bf16x8 sKh, sKl, sVh;

#define LOADT(KT) do {                                                                \
        const size_t gK = kbase + ((size_t)((KT) * 64 + srow)) * 64 + sc16 * 8;       \
        const size_t gV = vbase + (size_t)srow * N_ + (KT) * 64 + sc16 * 8;           \
        sKh = *(const bf16x8*)&kh[gK];                                                \
        sKl = *(const bf16x8*)&kl[gK];                                                \
        sVh = *(const bf16x8*)&vth[gV];                                               \
    } while (0)

#define WRITET(BB) do {                                                               \
        *(bf16x8*)&Kb[BB][0][kdst] = sKh;                                             \
        *(bf16x8*)&Kb[BB][1][kdst] = sKl;                                             \
        *(bf16x8*)&Vb[BB][vdst] = sVh;                                                \
    } while (0)

// QK^T j-tile (3-term) into S from Kb[BUF]
#define QKT_J(J, BUF, S) do {                                                         \
        const int krow_ = (J) * 16 + l15;                                             \
        const int rb_ = krow_ * 64, sw_ = (krow_ & 7) * 8;                            \
        _Pragma("unroll")                                                             \
        for (int c = 0; c < 2; ++c) {                                                 \
            const int off_ = rb_ + (((c * 4 + g) * 8) ^ sw_);                         \
            bf16x8 kfh_ = *(const bf16x8*)&Kb[BUF][0][off_];                          \
            bf16x8 kfl_ = *(const bf16x8*)&Kb[BUF][1][off_];                          \
            S[J] = __builtin_amdgcn_mfma_f32_16x16x32_bf16(kfh_, qf[c][0], S[J], 0, 0, 0); \
            S[J] = __builtin_amdgcn_mfma_f32_16x16x32_bf16(kfl_, qf[c][0], S[J], 0, 0, 0); \
            S[J] = __builtin_amdgcn_mfma_f32_16x16x32_bf16(kfh_, qf[c][1], S[J], 0, 0, 0); \
        }                                                                             \
    } while (0)

// online softmax over S[0..3] -> pah fragments (log2 domain, defer-max thr=8)
#define SOFTMAX_T(S) do {                                                             \
        float pmax_ = -3.0e38f;                                                       \
        _Pragma("unroll")                                                             \
        for (int j = 0; j < 4; ++j)                                                   \
            _Pragma("unroll")                                                         \
            for (int r = 0; r < 4; ++r) pmax_ = fmaxf(pmax_, S[j][r]);                \
        pmax_ = fmaxf(pmax_, __shfl_xor(pmax_, 16));                                  \
        pmax_ = fmaxf(pmax_, __shfl_xor(pmax_, 32));                                  \
        const float mold_ = mreg;                                                     \
        if (!__all(pmax_ <= mold_ + 8.0f)) {                                          \
            const float mnew_ = fmaxf(mold_, pmax_);                                  \
            const float alpha_ = exp2f(mold_ - mnew_);                                \
            _Pragma("unroll")                                                         \
            for (int dt = 0; dt < 4; ++dt)                                            \
                _Pragma("unroll")                                                     \
                for (int r = 0; r < 4; ++r) O[dt][r] *= alpha_;                       \
            lreg *= alpha_;                                                           \
            mreg = mnew_;                                                             \
        }                                                                             \
        const float mb_ = mreg;                                                       \
        float lsum_ = 0.f;                                                            \
        _Pragma("unroll")                                                             \
        for (int j = 0; j < 4; ++j)                                                   \
            _Pragma("unroll")                                                         \
            for (int r = 0; r < 4; ++r) {                                             \
                S[j][r] = exp2f(S[j][r] - mb_);                                       \
                lsum_ += S[j][r];                                                     \
            }                                                                         \
        lreg += lsum_;                                                                \
        _Pragma("unroll")                                                             \
        for (int c = 0; c < 2; ++c) {                                                 \
            union { unsigned int u[4]; bf16x8 v; } th_;                               \
            th_.u[0] = cvt_pk_bf16(S[2*c][0], S[2*c][1]);                             \
            th_.u[1] = cvt_pk_bf16(S[2*c][2], S[2*c][3]);                             \
            th_.u[2] = cvt_pk_bf16(S[2*c+1][0], S[2*c+1][1]);                         \
            th_.u[3] = cvt_pk_bf16(S[2*c+1][2], S[2*c+1][3]);                         \
            pah[c] = th_.v;                                                           \
        }                                                                             \
    } while (0)

// PV single-term: O += Vh[BUF] . P^T
#define PVSTEP(BUF) do {                                                              \
        _Pragma("unroll")                                                             \
        for (int c = 0; c < 2; ++c)                                                   \
            _Pragma("unroll")                                                         \
            for (int dt = 0; dt < 4; ++dt) {                                          \
                const int vrow_ = dt * 16 + l15;                                      \
                const int off_ = vrow_ * 64 + (((c * 4 + g) * 8) ^ ((vrow_ & 7) * 8));\
                bf16x8 vfh_ = *(const bf16x8*)&Vb[BUF][off_];                         \
                O[dt] = __builtin_amdgcn_mfma_f32_16x16x32_bf16(vfh_, pah[c], O[dt], 0, 0, 0); \
            }                                                                         \
    } while (0)

// one pipeline iteration: QK^T(T) into SC, finish tile T-1 from SP
#define ITER(T, BK, SC, SP) do {                                                      \
        if ((T) < 63) LOADT((T) + 1);                                                 \
        __builtin_amdgcn_s_setprio(1);                                                \
        SC[0] = (f32x4){0.f,0.f,0.f,0.f}; SC[1] = (f32x4){0.f,0.f,0.f,0.f};           \
        SC[2] = (f32x4){0.f,0.f,0.f,0.f}; SC[3] = (f32x4){0.f,0.f,0.f,0.f};           \
        QKT_J(0, BK, SC); QKT_J(1, BK, SC);                                           \
        SOFTMAX_T(SP);                                                                \
        QKT_J(2, BK, SC); QKT_J(3, BK, SC);                                           \
        PVSTEP((BK) ^ 1);                                                             \
        __builtin_amdgcn_s_setprio(0);                                                \
        __syncthreads();                                                              \
        if ((T) < 63) WRITET((BK) ^ 1);                                               \
        __syncthreads();                                                              \
    } while (0)

    f32x4 Sa[4], Sb[4];
    bf16x8 pah[2];

    // prologue: tile 0 staged + QK^T(0); tile 1 staged behind it
    LOADT(0); WRITET(0); __syncthreads();
    LOADT(1);
#pragma unroll
    for (int j = 0; j < 4; ++j) Sa[j] = (f32x4){0.f, 0.f, 0.f, 0.f};
    __builtin_amdgcn_s_setprio(1);
    QKT_J(0, 0, Sa); QKT_J(1, 0, Sa); QKT_J(2, 0, Sa); QKT_J(3, 0, Sa);
    __builtin_amdgcn_s_setprio(0);
    WRITET(1);
    __syncthreads();

    for (int tt = 1; tt < 64; tt += 2) {
        ITER(tt, 1, Sb, Sa);                       // odd tile -> Sb, finish Sa
        if (tt + 1 < 64) ITER(tt + 1, 0, Sa, Sb);  // even tile -> Sa, finish Sb
    }
    // drain tile 63 (odd -> Sb; its V tile sits in Vb[1])
    SOFTMAX_T(Sb);
    PVSTEP(1);

    // ---- epilogue: normalize, split to bf16 hi/lo, write [b n][h*64+d] ----
    const int b = bh >> 3, hh = bh & 7;
    {
        float lt = lreg;
        lt += __shfl_xor(lt, 16);
        lt += __shfl_xor(lt, 32);
        const float inv = 1.0f / lt;
        const int n = qbase + l15;
        const size_t rowbase = ((size_t)(b * N_) + n) * 512 + hh * 64 + g * 4;
#pragma unroll
        for (int dt = 0; dt < 4; ++dt) {
            const float s0 = O[dt][0] * inv, s1 = O[dt][1] * inv,
                        s2 = O[dt][2] * inv, s3 = O[dt][3] * inv;
            ushort4 hv, lv;
            hv.x = f2bf(s0); hv.y = f2bf(s1); hv.z = f2bf(s2); hv.w = f2bf(s3);
            lv.x = f2bf(s0 - bf2f(hv.x)); lv.y = f2bf(s1 - bf2f(hv.y));
            lv.z = f2bf(s2 - bf2f(hv.z)); lv.w = f2bf(s3 - bf2f(hv.w));
            *(ushort4*)&oh[rowbase + dt * 16] = hv;
            *(ushort4*)&ol[rowbase + dt * 16] = lv;
        }
    }
#undef LOADT
#undef WRITET
#undef QKT_J
#undef SOFTMAX_T
#undef PVSTEP
#undef ITER
}

// ---------------------------------------------------------------------------
extern "C" void kernel_launch(void* const* d_in, const int* in_sizes, int n_in,
                              void* d_out, int out_size, void* d_ws, size_t ws_size,
                              hipStream_t stream)
{
    const float* x  = (const float*)d_in[0];
    const float* Wq = (const float*)d_in[1];
    const float* Wk = (const float*)d_in[2];
    const float* Wv = (const float*)d_in[3];
    const float* Wo = (const float*)d_in[4];
    const float* bo = (const float*)d_in[5];

    unsigned char* w8 = (unsigned char*)d_ws;
    const size_t MB = 1024 * 1024;
    unsigned short* xh  = (unsigned short*)(w8);            // 8 MB
    unsigned short* xl  = (unsigned short*)(w8 + 8  * MB);  // 8 MB
    unsigned short* wh  = (unsigned short*)(w8 + 16 * MB);  // 2 MB [4][512][512]
    unsigned short* wl  = (unsigned short*)(w8 + 18 * MB);  // 2 MB
    unsigned short* qh  = (unsigned short*)(w8 + 20 * MB);
    unsigned short* ql  = (unsigned short*)(w8 + 28 * MB);
    unsigned short* kh  = (unsigned short*)(w8 + 36 * MB);
    unsigned short* kl  = (unsigned short*)(w8 + 44 * MB);
    unsigned short* vth = (unsigned short*)(w8 + 52 * MB);  // end 60 MB
    // att (split) aliases xh/xl: x is dead once the QKV GEMMs complete.
    unsigned short* ah = xh;
    unsigned short* al = xl;
    float* out = (float*)d_out;

    conv_all<<<5120, 256, 0, stream>>>(x, Wq, Wk, Wv, Wo, xh, xl, wh, wl);

    // fused QKV: grid y 0-3 -> q (scaled), 4-7 -> k, 8-11 -> v (hi, transposed)
    gemm_mfma<1><<<dim3(64, 12), 256, 0, stream>>>(xh, xl, wh, wl, nullptr, nullptr,
                                                   qh, ql, kh, kl, vth, nullptr, QSCALE_);

    attn_mfma<<<dim3(N_ / 128, 16), 512, 0, stream>>>(qh, ql, kh, kl, vth, ah, al);

    // final projection + bias
    gemm_mfma<0><<<dim3(64, 4), 256, 0, stream>>>(ah, al, wh + 3 * 262144, wl + 3 * 262144,
                                                  bo, out, nullptr, nullptr, nullptr, nullptr,
                                                  nullptr, nullptr, 1.0f);
}